// Round 3
// baseline (2716.204 us; speedup 1.0000x reference)
//
#include <hip/hip_runtime.h>
#include <hip/hip_bf16.h>
#include <cstdio>

typedef __hip_bfloat16 bf16;

#define NB    32
#define NK    256
#define NDIN  512
#define NPROJ 64
#define NDM   128
#define NNL   3
#define NT    63
#define NDI   256
#define NSEQ  2048            // NB*NPROJ
#define NROW  (NSEQ*NT)       // 129024

static __device__ __forceinline__ float b2f(bf16 v){ return __bfloat162float(v); }
static __device__ __forceinline__ bf16  f2b(float v){ return __float2bfloat16(v); }
static __device__ __forceinline__ float siluf(float x){ return x / (1.f + __expf(-x)); }
static __device__ __forceinline__ float softplusf(float x){
  float e = __expf(-fabsf(x));
  return fmaxf(x, 0.f) + __logf(1.f + e);
}

// ---------------------------------------------------------------------------
// 1) hp[n][k] = x[b,k,:] . W_proj[:,p] + b_proj[p],  n = b*64+p  (transposed)
__global__ void k_proj(const float* __restrict__ x, const float* __restrict__ Wp,
                       const float* __restrict__ bp, float* __restrict__ hp)
{
  int blk = blockIdx.x;            // b*256 + k
  int b = blk >> 8, k = blk & 255;
  __shared__ float xr[NDIN];
  for (int i = threadIdx.x; i < NDIN; i += 64)
    xr[i] = x[(size_t)blk*NDIN + i];
  __syncthreads();
  int p = threadIdx.x;
  float acc = bp[p];
  #pragma unroll 8
  for (int d = 0; d < NDIN; ++d)
    acc += xr[d] * Wp[d*NPROJ + p];
  hp[(size_t)(b*NPROJ + p)*NK + k] = acc;
}

// ---------------------------------------------------------------------------
// 2) u[n,t,m] = sum_j hp[n][t*4+j] * We[j][m] + be[m]
__global__ void k_embed(const float* __restrict__ hp, const float* __restrict__ We,
                        const float* __restrict__ be, float* __restrict__ u)
{
  int blk = blockIdx.x;            // n*63 + t
  int n = blk / NT, t = blk - n*NT;
  int m = threadIdx.x;
  const float* hr = hp + (size_t)n*NK + t*4;
  float acc = be[m];
  #pragma unroll
  for (int j = 0; j < 8; ++j)
    acc += hr[j] * We[j*NDM + m];
  u[(size_t)blk*NDM + m] = acc;
}

// ---------------------------------------------------------------------------
// 3) per-row rms scale. u already offset to chunk base.
__global__ void k_rms(const float* __restrict__ u, float* __restrict__ scale)
{
  int row = blockIdx.x;
  float v = u[(size_t)row*NDM + threadIdx.x];
  float s = v*v;
  #pragma unroll
  for (int o = 32; o > 0; o >>= 1) s += __shfl_down(s, o);
  __shared__ float ws[2];
  if ((threadIdx.x & 63) == 0) ws[threadIdx.x >> 6] = s;
  __syncthreads();
  if (threadIdx.x == 0) scale[row] = rsqrtf((ws[0]+ws[1]) * (1.f/NDM) + 1e-5f);
}

// ---------------------------------------------------------------------------
// 4) Tiled GEMM, BM=BN=BK=64, 256 threads, 4x4 microtile. All ptrs chunk-local.
//    MODE 0: in_proj : A = u(f32 s128)*scale[row]*nw[k], B f32 s512,
//                      store bf16: col<256 -> Cptr(xh, s256), else Cptr2(z, s256)
//    MODE 1: x_proj  : A = xh bf16 s256, B f32 s40 (zero-pad to 64),
//                      store f32 cols<40 -> Cptr(dbl, s40)
//    MODE 2: out_proj: A = xh bf16 s256, B f32 s128, C: f32 u += (s128)
template<int MODE, int KT>
__global__ void k_gemm(const void* __restrict__ Aptr, const float* __restrict__ Bptr,
                       void* __restrict__ Cptr, void* __restrict__ Cptr2,
                       const float* __restrict__ scale, const float* __restrict__ nw)
{
  __shared__ __align__(16) float As[64][68];   // [k][m], padded
  __shared__ __align__(16) float Bs[64][64];   // [k][n]
  const int r0 = blockIdx.x * 64;
  const int n0 = blockIdx.y * 64;
  const int tid = threadIdx.x;
  const int tr = (tid >> 4) << 2;
  const int tc = (tid & 15) << 2;
  float acc[4][4] = {};

  for (int kc = 0; kc < KT; kc += 64) {
    #pragma unroll
    for (int j = 0; j < 16; ++j) {
      int e  = tid + j*256;
      int rr = e >> 6, kk = e & 63;
      float v;
      if (MODE == 0) {
        v = ((const float*)Aptr)[(size_t)(r0+rr)*KT + kc + kk]
            * scale[r0+rr] * nw[kc+kk];
      } else {
        v = b2f(((const bf16*)Aptr)[(size_t)(r0+rr)*KT + kc + kk]);
      }
      As[kk][rr] = v;
    }
    #pragma unroll
    for (int j = 0; j < 16; ++j) {
      int e  = tid + j*256;
      int kk = e >> 6, nn = e & 63;
      float v;
      if (MODE == 1) {
        int col = n0 + nn;
        v = (col < 40) ? Bptr[(size_t)(kc+kk)*40 + col] : 0.f;
      } else if (MODE == 0) {
        v = Bptr[(size_t)(kc+kk)*512 + n0 + nn];
      } else {
        v = Bptr[(size_t)(kc+kk)*128 + n0 + nn];
      }
      Bs[kk][nn] = v;
    }
    __syncthreads();
    #pragma unroll
    for (int k = 0; k < 64; ++k) {
      float4 av = *(const float4*)&As[k][tr];
      float4 bv = *(const float4*)&Bs[k][tc];
      acc[0][0] += av.x*bv.x; acc[0][1] += av.x*bv.y; acc[0][2] += av.x*bv.z; acc[0][3] += av.x*bv.w;
      acc[1][0] += av.y*bv.x; acc[1][1] += av.y*bv.y; acc[1][2] += av.y*bv.z; acc[1][3] += av.y*bv.w;
      acc[2][0] += av.z*bv.x; acc[2][1] += av.z*bv.y; acc[2][2] += av.z*bv.z; acc[2][3] += av.z*bv.w;
      acc[3][0] += av.w*bv.x; acc[3][1] += av.w*bv.y; acc[3][2] += av.w*bv.z; acc[3][3] += av.w*bv.w;
    }
    __syncthreads();
  }
  #pragma unroll
  for (int i = 0; i < 4; ++i) {
    int row = r0 + tr + i;
    #pragma unroll
    for (int j = 0; j < 4; ++j) {
      int col = n0 + tc + j;
      if (MODE == 0) {
        if (col < 256) ((bf16*)Cptr )[(size_t)row*256 + col]       = f2b(acc[i][j]);
        else           ((bf16*)Cptr2)[(size_t)row*256 + col - 256] = f2b(acc[i][j]);
      } else if (MODE == 1) {
        if (col < 40) ((float*)Cptr)[(size_t)row*40 + col] = acc[i][j];
      } else {
        float* p = (float*)Cptr + (size_t)row*128 + col;
        *p += acc[i][j];
      }
    }
  }
}

// ---------------------------------------------------------------------------
// 5) depthwise causal conv(4) + bias + silu, IN PLACE on xh (stride 256).
__global__ void k_conv(bf16* __restrict__ xh,
                       const float* __restrict__ cw, const float* __restrict__ cb)
{
  int n = blockIdx.x, d = threadIdx.x;
  float w0 = cw[d*4+0], w1 = cw[d*4+1];
  float w2 = cw[d*4+2], w3 = cw[d*4+3];
  float bias = cb[d];
  float xm3 = 0.f, xm2 = 0.f, xm1 = 0.f;
  bf16* ptr = xh + (size_t)n*NT*256 + d;
  for (int t = 0; t < NT; ++t) {
    float xt = b2f(ptr[(size_t)t*256]);
    float a  = bias + w0*xm3 + w1*xm2 + w2*xm1 + w3*xt;
    ptr[(size_t)t*256] = f2b(siluf(a));
    xm3 = xm2; xm2 = xm1; xm1 = xt;
  }
}

// ---------------------------------------------------------------------------
// 6) fused dt_proj + softplus + selective scan + skip + silu(z) gating.
//    y written in place over xh. All ptrs chunk-local.
__global__ void k_scan(const float* __restrict__ dbl, const bf16* __restrict__ z,
                       bf16* __restrict__ xh,
                       const float* __restrict__ Wdt, const float* __restrict__ bdt,
                       const float* __restrict__ Alog, const float* __restrict__ Dpp)
{
  int n = blockIdx.x, d = threadIdx.x;
  __shared__ float sd[NT][40];    // dt(8) | B(16) | C(16)
  for (int i = threadIdx.x; i < NT*40; i += 256)
    sd[i/40][i%40] = dbl[(size_t)n*NT*40 + i];
  __syncthreads();

  float wdt[8];
  #pragma unroll
  for (int r = 0; r < 8; ++r) wdt[r] = Wdt[r*256 + d];
  float bd = bdt[d];
  float Av[16];
  #pragma unroll
  for (int s = 0; s < 16; ++s) Av[s] = -__expf(Alog[d*16 + s]);
  float dp = Dpp[d];
  float h[16];
  #pragma unroll
  for (int s = 0; s < 16; ++s) h[s] = 0.f;

  const bf16* zsrc = z  + (size_t)n*NT*256 + d;
  bf16*       uio  = xh + (size_t)n*NT*256 + d;
  for (int t = 0; t < NT; ++t) {
    float dtv = bd;
    #pragma unroll
    for (int r = 0; r < 8; ++r) dtv += sd[t][r]*wdt[r];
    float delta = softplusf(dtv);
    float ut = b2f(uio[(size_t)t*256]);
    float du = delta*ut;
    float yt = 0.f;
    #pragma unroll
    for (int s = 0; s < 16; ++s) {
      float e = __expf(delta*Av[s]);
      h[s] = h[s]*e + du*sd[t][8+s];
      yt  += h[s]*sd[t][24+s];
    }
    float zv = b2f(zsrc[(size_t)t*256]);
    float y  = (yt + ut*dp) * siluf(zv);
    uio[(size_t)t*256] = f2b(y);
  }
}

// ---------------------------------------------------------------------------
// 7) final rmsnorm + flat head
__global__ void k_head(const float* __restrict__ u, const float* __restrict__ fnw,
                       const float* __restrict__ hw, const float* __restrict__ hfb,
                       float* __restrict__ y1)
{
  int n = blockIdx.x, m = threadIdx.x;
  float fw = fnw[m];
  float accp = 0.f;
  __shared__ float ws[2];
  for (int t = 0; t < NT; ++t) {
    float v = u[((size_t)n*NT + t)*NDM + m];
    float s = v*v;
    #pragma unroll
    for (int o = 32; o > 0; o >>= 1) s += __shfl_down(s, o);
    if ((m & 63) == 0) ws[m >> 6] = s;
    __syncthreads();
    float tot = ws[0] + ws[1];
    __syncthreads();
    float sc = rsqrtf(tot * (1.f/NDM) + 1e-5f);
    accp += v*sc*fw*hw[t*NDM + m];
  }
  #pragma unroll
  for (int o = 32; o > 0; o >>= 1) accp += __shfl_down(accp, o);
  if ((m & 63) == 0) ws[m >> 6] = accp;
  __syncthreads();
  if (m == 0) y1[n] = ws[0] + ws[1] + hfb[0];
}

// ---------------------------------------------------------------------------
// 8) out[b,c] = sum_p y1[b*64+p]*Wh[p,c] + bh[c].
__global__ void k_final(const float* __restrict__ y1, const float* __restrict__ Wh,
                        const float* __restrict__ bh, float* __restrict__ out)
{
  int t = threadIdx.x;
  int b = t >> 1, c = t & 1;
  float acc = bh[c];
  #pragma unroll 8
  for (int p = 0; p < 64; ++p) acc += y1[b*64 + p]*Wh[p*2 + c];
  out[b*2 + c] = acc;
}

// ---------------------------------------------------------------------------
extern "C" void kernel_launch(void* const* d_in, const int* in_sizes, int n_in,
                              void* d_out, int out_size, void* d_ws, size_t ws_size,
                              hipStream_t stream)
{
  const float* x    = (const float*)d_in[0];
  const float* Wp   = (const float*)d_in[1];
  const float* bp   = (const float*)d_in[2];
  const float* We   = (const float*)d_in[3];
  const float* be   = (const float*)d_in[4];
  const float* nrm  = (const float*)d_in[5];
  const float* Wi   = (const float*)d_in[6];
  const float* cw   = (const float*)d_in[7];
  const float* cb   = (const float*)d_in[8];
  const float* Wx   = (const float*)d_in[9];
  const float* Wdt  = (const float*)d_in[10];
  const float* bdt  = (const float*)d_in[11];
  const float* Alog = (const float*)d_in[12];
  const float* Dpp  = (const float*)d_in[13];
  const float* Wo   = (const float*)d_in[14];
  const float* fnw  = (const float*)d_in[15];
  const float* hw   = (const float*)d_in[16];
  const float* hfb  = (const float*)d_in[17];
  const float* Wh   = (const float*)d_in[18];
  const float* bh   = (const float*)d_in[19];

  // ---- adaptive chunking over sequences ----
  const size_t fixed_b = (size_t)NROW*NDM*4 + (size_t)NSEQ*NK*4 + NSEQ*4 + 4096;
  const size_t per_seq = (size_t)NT*256*2*2 + (size_t)NT*40*4 + NT*4;
  int ch_seq = NSEQ;
  while (ch_seq > 64 && fixed_b + (size_t)ch_seq*per_seq + 2048 > ws_size)
    ch_seq >>= 1;
  const int nchunk  = NSEQ / ch_seq;
  const int ch_rows = ch_seq * NT;
  fprintf(stderr, "[mamba] ws_size=%zu ch_seq=%d nchunk=%d\n",
          ws_size, ch_seq, nchunk);

  char* pw = (char*)d_ws;
  float* u    = (float*)pw; pw += (size_t)NROW*NDM*4;
  float* hp   = (float*)pw; pw += (size_t)NSEQ*NK*4;
  float* y1   = (float*)pw; pw += (size_t)NSEQ*4;
  float* dbl  = (float*)pw; pw += (size_t)ch_rows*40*4;
  float* scal = (float*)pw; pw += (size_t)ch_rows*4;
  bf16*  xh   = (bf16*)pw;  pw += (size_t)ch_rows*256*2;
  bf16*  z    = (bf16*)pw;  pw += (size_t)ch_rows*256*2;

  k_proj <<<NB*NK,  64, 0, stream>>>(x, Wp, bp, hp);
  k_embed<<<NROW,  128, 0, stream>>>(hp, We, be, u);

  for (int l = 0; l < NNL; ++l) {
    const float* Wi_l  = Wi   + (size_t)l*NDM*512;
    const float* nw_l  = nrm  + (size_t)l*NDM;
    const float* cw_l  = cw   + (size_t)l*NDI*4;
    const float* cb_l  = cb   + (size_t)l*NDI;
    const float* Wx_l  = Wx   + (size_t)l*NDI*40;
    const float* Wdt_l = Wdt  + (size_t)l*8*NDI;
    const float* bdt_l = bdt  + (size_t)l*NDI;
    const float* Al_l  = Alog + (size_t)l*NDI*16;
    const float* Dp_l  = Dpp  + (size_t)l*NDI;
    const float* Wo_l  = Wo   + (size_t)l*NDI*NDM;

    for (int c = 0; c < nchunk; ++c) {
      float* u_c = u + (size_t)c*ch_rows*NDM;
      k_rms<<<ch_rows, 128, 0, stream>>>(u_c, scal);
      k_gemm<0,128><<<dim3(ch_rows/64, 8), 256, 0, stream>>>(
          u_c, Wi_l, xh, z, scal, nw_l);
      k_conv<<<ch_seq, 256, 0, stream>>>(xh, cw_l, cb_l);
      k_gemm<1,256><<<dim3(ch_rows/64, 1), 256, 0, stream>>>(
          xh, Wx_l, dbl, nullptr, nullptr, nullptr);
      k_scan<<<ch_seq, 256, 0, stream>>>(dbl, z, xh, Wdt_l, bdt_l, Al_l, Dp_l);
      k_gemm<2,256><<<dim3(ch_rows/64, 2), 256, 0, stream>>>(
          xh, Wo_l, u_c, nullptr, nullptr, nullptr);
    }
  }

  k_head <<<NSEQ, 128, 0, stream>>>(u, fnw, hw, hfb, y1);
  k_final<<<1, 64, 0, stream>>>(y1, Wh, bh, (float*)d_out);
}

// Round 4
// 1222.283 us; speedup vs baseline: 2.2222x; 2.2222x over previous
//
#include <hip/hip_runtime.h>
#include <hip/hip_bf16.h>
#include <cstdio>

typedef __hip_bfloat16 bf16;
typedef __attribute__((ext_vector_type(8))) short short8;   // 8 bf16 = 4 VGPR
typedef __attribute__((ext_vector_type(4))) short short4v;
typedef __attribute__((ext_vector_type(4))) float f32x4;

#define NB    32
#define NK    256
#define NDIN  512
#define NPROJ 64
#define NDM   128
#define NNL   3
#define NT    63
#define NDI   256
#define NSEQ  2048            // NB*NPROJ
#define NROW  (NSEQ*NT)       // 129024
#define LDP   136             // LDS K-stride in shorts (17 * 16B -> conflict-free b128)

static __device__ __forceinline__ float b2f(bf16 v){ return __bfloat162float(v); }
static __device__ __forceinline__ bf16  f2b(float v){ return __float2bfloat16(v); }
static __device__ __forceinline__ unsigned short f2bs(float v){   // RNE f32->bf16 bits
  unsigned int u = __float_as_uint(v);
  return (unsigned short)((u + 0x7FFFu + ((u >> 16) & 1u)) >> 16);
}
static __device__ __forceinline__ float siluf(float x){ return x / (1.f + __expf(-x)); }
static __device__ __forceinline__ float softplusf(float x){
  float e = __expf(-fabsf(x));
  return fmaxf(x, 0.f) + __logf(1.f + e);
}

// ---------------------------------------------------------------------------
// weight pre-transpose to K-major bf16: dst[n*K+k] = src[k*srcN+n] (0 if n>=nvalid)
__global__ void k_tw(const float* __restrict__ src, unsigned short* __restrict__ dst,
                     int K, int srcN, int nvalid)
{
  int n = blockIdx.x;
  for (int k = threadIdx.x; k < K; k += blockDim.x) {
    float v = (n < nvalid) ? src[(size_t)k*srcN + n] : 0.f;
    dst[(size_t)n*K + k] = f2bs(v);
  }
}

// ---------------------------------------------------------------------------
// 1) hp[n][k] = x[b,k,:] . W_proj[:,p] + b_proj[p]
__global__ void k_proj(const float* __restrict__ x, const float* __restrict__ Wp,
                       const float* __restrict__ bp, float* __restrict__ hp)
{
  int blk = blockIdx.x;            // b*256 + k
  int b = blk >> 8, k = blk & 255;
  __shared__ float xr[NDIN];
  for (int i = threadIdx.x; i < NDIN; i += 64)
    xr[i] = x[(size_t)blk*NDIN + i];
  __syncthreads();
  int p = threadIdx.x;
  float acc = bp[p];
  #pragma unroll 8
  for (int d = 0; d < NDIN; ++d)
    acc += xr[d] * Wp[d*NPROJ + p];
  hp[(size_t)(b*NPROJ + p)*NK + k] = acc;
}

// ---------------------------------------------------------------------------
// 2) u[n,t,m] = sum_j hp[n][t*4+j] * We[j][m] + be[m]
__global__ void k_embed(const float* __restrict__ hp, const float* __restrict__ We,
                        const float* __restrict__ be, float* __restrict__ u)
{
  int blk = blockIdx.x;            // n*63 + t
  int n = blk / NT, t = blk - n*NT;
  int m = threadIdx.x;
  const float* hr = hp + (size_t)n*NK + t*4;
  float acc = be[m];
  #pragma unroll
  for (int j = 0; j < 8; ++j)
    acc += hr[j] * We[j*NDM + m];
  u[(size_t)blk*NDM + m] = acc;
}

// ---------------------------------------------------------------------------
// 3) per-row rms scale
__global__ void k_rms(const float* __restrict__ u, float* __restrict__ scale)
{
  int row = blockIdx.x;
  float v = u[(size_t)row*NDM + threadIdx.x];
  float s = v*v;
  #pragma unroll
  for (int o = 32; o > 0; o >>= 1) s += __shfl_down(s, o);
  __shared__ float ws[2];
  if ((threadIdx.x & 63) == 0) ws[threadIdx.x >> 6] = s;
  __syncthreads();
  if (threadIdx.x == 0) scale[row] = rsqrtf((ws[0]+ws[1]) * (1.f/NDM) + 1e-5f);
}

// ---------------------------------------------------------------------------
// 4) MFMA GEMM. BM=64, BN=128 or 64, 256 threads (4 waves, 2x2), wave tile 32x(BN/2).
//    A/B staged K-major bf16 in LDS (stride LDP), frags via ds_read_b128,
//    v_mfma_f32_16x16x32_bf16.
//    MODE 0: in_proj : A = u(f32 s128)*scale*nw -> bf16; B = WiT[512][128];
//                      C bf16: global col<256 -> xh(s256) else z(s256).  K=128
//    MODE 1: x_proj  : A = xh bf16 s256; B = WxT[64][256] (rows>=40 zero);
//                      C f32 dbl(s40), col<40.                           K=256
//    MODE 2: out_proj: A = xh bf16 s256; B = WoT[128][256]; C: u += (s128). K=256
template<int MODE, int KTOT, int BN>
__global__ __launch_bounds__(256) void
k_mgemm(const void* __restrict__ Aptr, const unsigned short* __restrict__ WT,
        void* __restrict__ Cptr, void* __restrict__ Cptr2,
        const float* __restrict__ scale, const float* __restrict__ nw)
{
  constexpr int MJ = BN/32;              // n-tiles per wave (4 or 2)
  __shared__ short As[64*LDP];
  __shared__ short Bs[BN*LDP];

  const int tid  = threadIdx.x;
  const int r0   = blockIdx.x * 64;
  const int n0   = (MODE == 0) ? blockIdx.y * 128 : 0;
  const int w    = tid >> 6;
  const int lane = tid & 63;
  const int l16  = lane & 15;
  const int quad = lane >> 4;
  const int WM   = (w >> 1) * 32;
  const int WN   = (w & 1) * (BN/2);

  f32x4 acc[2][MJ] = {};

  for (int kc = 0; kc < KTOT; kc += 128) {
    // ---- stage A (64 rows x 128 k) ----
    if (MODE == 0) {
      #pragma unroll
      for (int j = 0; j < 8; ++j) {
        int c   = tid + j*256;          // float4 chunk
        int row = c >> 5, k4 = (c & 31) << 2;
        float4 v = *(const float4*)((const float*)Aptr + (size_t)(r0+row)*128 + k4);
        float  sc = scale[r0+row];
        const float4 nwv = *(const float4*)(nw + k4);
        short4v o = { (short)f2bs(v.x*sc*nwv.x), (short)f2bs(v.y*sc*nwv.y),
                      (short)f2bs(v.z*sc*nwv.z), (short)f2bs(v.w*sc*nwv.w) };
        *(short4v*)&As[row*LDP + k4] = o;
      }
    } else {
      #pragma unroll
      for (int j = 0; j < 4; ++j) {
        int c   = tid + j*256;          // 16B chunk
        int row = c >> 4, k8 = (c & 15) << 3;
        short8 v = *(const short8*)((const unsigned short*)Aptr
                                    + (size_t)(r0+row)*256 + kc + k8);
        *(short8*)&As[row*LDP + k8] = v;
      }
    }
    // ---- stage B (BN rows x 128 k) from K-major WT ----
    #pragma unroll
    for (int j = 0; j < BN/16; ++j) {
      int c  = tid + j*256;
      int n  = c >> 4, k8 = (c & 15) << 3;
      short8 v = *(const short8*)(WT + (size_t)(n0+n)*KTOT + kc + k8);
      *(short8*)&Bs[n*LDP + k8] = v;
    }
    __syncthreads();

    #pragma unroll
    for (int ks = 0; ks < 4; ++ks) {
      short8 a[2], b[MJ];
      #pragma unroll
      for (int i = 0; i < 2; ++i)
        a[i] = *(const short8*)&As[(WM + i*16 + l16)*LDP + ks*32 + quad*8];
      #pragma unroll
      for (int j = 0; j < MJ; ++j)
        b[j] = *(const short8*)&Bs[(WN + j*16 + l16)*LDP + ks*32 + quad*8];
      #pragma unroll
      for (int i = 0; i < 2; ++i)
        #pragma unroll
        for (int j = 0; j < MJ; ++j)
          acc[i][j] = __builtin_amdgcn_mfma_f32_16x16x32_bf16(a[i], b[j], acc[i][j], 0, 0, 0);
    }
    __syncthreads();
  }

  // ---- epilogue ----
  #pragma unroll
  for (int i = 0; i < 2; ++i) {
    #pragma unroll
    for (int j = 0; j < MJ; ++j) {
      #pragma unroll
      for (int rr = 0; rr < 4; ++rr) {
        int row = r0 + WM + i*16 + quad*4 + rr;
        int col = n0 + WN + j*16 + l16;
        float v = acc[i][j][rr];
        if (MODE == 0) {
          if (col < 256) ((unsigned short*)Cptr )[(size_t)row*256 + col]       = f2bs(v);
          else           ((unsigned short*)Cptr2)[(size_t)row*256 + col - 256] = f2bs(v);
        } else if (MODE == 1) {
          if (col < 40) ((float*)Cptr)[(size_t)row*40 + col] = v;
        } else {
          ((float*)Cptr)[(size_t)row*128 + col] += v;
        }
      }
    }
  }
}

// ---------------------------------------------------------------------------
// 5) depthwise causal conv(4) + bias + silu, IN PLACE on xh (stride 256).
__global__ __launch_bounds__(256) void k_conv(bf16* __restrict__ xh,
                       const float* __restrict__ cw, const float* __restrict__ cb)
{
  int n = blockIdx.x, d = threadIdx.x;
  float w0 = cw[d*4+0], w1 = cw[d*4+1];
  float w2 = cw[d*4+2], w3 = cw[d*4+3];
  float bias = cb[d];
  float xm3 = 0.f, xm2 = 0.f, xm1 = 0.f;
  bf16* ptr = xh + (size_t)n*NT*256 + d;
  for (int t = 0; t < NT; ++t) {
    float xt = b2f(ptr[(size_t)t*256]);
    float a  = bias + w0*xm3 + w1*xm2 + w2*xm1 + w3*xt;
    ptr[(size_t)t*256] = f2b(siluf(a));
    xm3 = xm2; xm2 = xm1; xm1 = xt;
  }
}

// ---------------------------------------------------------------------------
// 6) fused dt_proj + softplus + selective scan + skip + silu(z) gating. In-place on xh.
__global__ __launch_bounds__(256) void k_scan(const float* __restrict__ dbl,
                       const bf16* __restrict__ z, bf16* __restrict__ xh,
                       const float* __restrict__ Wdt, const float* __restrict__ bdt,
                       const float* __restrict__ Alog, const float* __restrict__ Dpp)
{
  int n = blockIdx.x, d = threadIdx.x;
  __shared__ float sd[NT][40];    // dt(8) | B(16) | C(16)
  for (int i = threadIdx.x; i < NT*40; i += 256)
    sd[i/40][i%40] = dbl[(size_t)n*NT*40 + i];
  __syncthreads();

  float wdt[8];
  #pragma unroll
  for (int r = 0; r < 8; ++r) wdt[r] = Wdt[r*256 + d];
  float bd = bdt[d];
  float Av[16];
  #pragma unroll
  for (int s = 0; s < 16; ++s) Av[s] = -__expf(Alog[d*16 + s]);
  float dp = Dpp[d];
  float h[16];
  #pragma unroll
  for (int s = 0; s < 16; ++s) h[s] = 0.f;

  const bf16* zsrc = z  + (size_t)n*NT*256 + d;
  bf16*       uio  = xh + (size_t)n*NT*256 + d;
  for (int t = 0; t < NT; ++t) {
    float dtv = bd;
    #pragma unroll
    for (int r = 0; r < 8; ++r) dtv += sd[t][r]*wdt[r];
    float delta = softplusf(dtv);
    float ut = b2f(uio[(size_t)t*256]);
    float du = delta*ut;
    float yt = 0.f;
    #pragma unroll
    for (int s = 0; s < 16; ++s) {
      float e = __expf(delta*Av[s]);
      h[s] = h[s]*e + du*sd[t][8+s];
      yt  += h[s]*sd[t][24+s];
    }
    float zv = b2f(zsrc[(size_t)t*256]);
    float y  = (yt + ut*dp) * siluf(zv);
    uio[(size_t)t*256] = f2b(y);
  }
}

// ---------------------------------------------------------------------------
// 7) final rmsnorm + flat head
__global__ __launch_bounds__(128) void k_head(const float* __restrict__ u,
                       const float* __restrict__ fnw,
                       const float* __restrict__ hw, const float* __restrict__ hfb,
                       float* __restrict__ y1)
{
  int n = blockIdx.x, m = threadIdx.x;
  float fw = fnw[m];
  float accp = 0.f;
  __shared__ float ws[2];
  for (int t = 0; t < NT; ++t) {
    float v = u[((size_t)n*NT + t)*NDM + m];
    float s = v*v;
    #pragma unroll
    for (int o = 32; o > 0; o >>= 1) s += __shfl_down(s, o);
    if ((m & 63) == 0) ws[m >> 6] = s;
    __syncthreads();
    float tot = ws[0] + ws[1];
    __syncthreads();
    float sc = rsqrtf(tot * (1.f/NDM) + 1e-5f);
    accp += v*sc*fw*hw[t*NDM + m];
  }
  #pragma unroll
  for (int o = 32; o > 0; o >>= 1) accp += __shfl_down(accp, o);
  if ((m & 63) == 0) ws[m >> 6] = accp;
  __syncthreads();
  if (m == 0) y1[n] = ws[0] + ws[1] + hfb[0];
}

// ---------------------------------------------------------------------------
// 8) out[b,c] = sum_p y1[b*64+p]*Wh[p,c] + bh[c].
__global__ __launch_bounds__(64) void k_final(const float* __restrict__ y1,
                        const float* __restrict__ Wh,
                        const float* __restrict__ bh, float* __restrict__ out)
{
  int t = threadIdx.x;
  int b = t >> 1, c = t & 1;
  float acc = bh[c];
  #pragma unroll 8
  for (int p = 0; p < 64; ++p) acc += y1[b*64 + p]*Wh[p*2 + c];
  out[b*2 + c] = acc;
}

// ---------------------------------------------------------------------------
extern "C" void kernel_launch(void* const* d_in, const int* in_sizes, int n_in,
                              void* d_out, int out_size, void* d_ws, size_t ws_size,
                              hipStream_t stream)
{
  const float* x    = (const float*)d_in[0];
  const float* Wp   = (const float*)d_in[1];
  const float* bp   = (const float*)d_in[2];
  const float* We   = (const float*)d_in[3];
  const float* be   = (const float*)d_in[4];
  const float* nrm  = (const float*)d_in[5];
  const float* Wi   = (const float*)d_in[6];
  const float* cw   = (const float*)d_in[7];
  const float* cb   = (const float*)d_in[8];
  const float* Wx   = (const float*)d_in[9];
  const float* Wdt  = (const float*)d_in[10];
  const float* bdt  = (const float*)d_in[11];
  const float* Alog = (const float*)d_in[12];
  const float* Dpp  = (const float*)d_in[13];
  const float* Wo   = (const float*)d_in[14];
  const float* fnw  = (const float*)d_in[15];
  const float* hw   = (const float*)d_in[16];
  const float* hfb  = (const float*)d_in[17];
  const float* Wh   = (const float*)d_in[18];
  const float* bh   = (const float*)d_in[19];

  // ---- adaptive chunking over sequences (measured ws = 256 MiB -> nchunk=1) ----
  const size_t fixed_b = (size_t)NROW*NDM*4 + (size_t)NSEQ*NK*4 + NSEQ*4
                       + 512*128*2 + 128*256*2 + 64*256*2 + 8192;
  const size_t per_seq = (size_t)NT*256*2*2 + (size_t)NT*40*4 + NT*4;
  int ch_seq = NSEQ;
  while (ch_seq > 128 && fixed_b + (size_t)ch_seq*per_seq + 2048 > ws_size)
    ch_seq >>= 1;
  const int nchunk  = NSEQ / ch_seq;
  const int ch_rows = ch_seq * NT;
  fprintf(stderr, "[mamba] ws_size=%zu ch_seq=%d nchunk=%d\n", ws_size, ch_seq, nchunk);

  char* pw = (char*)d_ws;
  float* u    = (float*)pw; pw += (size_t)NROW*NDM*4;
  float* hp   = (float*)pw; pw += (size_t)NSEQ*NK*4;
  float* y1   = (float*)pw; pw += (size_t)NSEQ*4;
  unsigned short* WiT = (unsigned short*)pw; pw += 512*128*2;
  unsigned short* WoT = (unsigned short*)pw; pw += 128*256*2;
  unsigned short* WxT = (unsigned short*)pw; pw += 64*256*2;
  float* dbl  = (float*)pw; pw += (size_t)ch_rows*40*4;
  float* scal = (float*)pw; pw += (size_t)ch_rows*4;
  bf16*  xh   = (bf16*)pw;  pw += (size_t)ch_rows*256*2;
  bf16*  z    = (bf16*)pw;  pw += (size_t)ch_rows*256*2;

  k_proj <<<NB*NK,  64, 0, stream>>>(x, Wp, bp, hp);
  k_embed<<<NROW,  128, 0, stream>>>(hp, We, be, u);

  for (int l = 0; l < NNL; ++l) {
    const float* Wi_l  = Wi   + (size_t)l*NDM*512;
    const float* nw_l  = nrm  + (size_t)l*NDM;
    const float* cw_l  = cw   + (size_t)l*NDI*4;
    const float* cb_l  = cb   + (size_t)l*NDI;
    const float* Wx_l  = Wx   + (size_t)l*NDI*40;
    const float* Wdt_l = Wdt  + (size_t)l*8*NDI;
    const float* bdt_l = bdt  + (size_t)l*NDI;
    const float* Al_l  = Alog + (size_t)l*NDI*16;
    const float* Dp_l  = Dpp  + (size_t)l*NDI;
    const float* Wo_l  = Wo   + (size_t)l*NDI*NDM;

    k_tw<<<512, 128, 0, stream>>>(Wi_l, WiT, 128, 512, 512);
    k_tw<<<128, 256, 0, stream>>>(Wo_l, WoT, 256, 128, 128);
    k_tw<<< 64, 256, 0, stream>>>(Wx_l, WxT, 256,  40,  40);

    for (int c = 0; c < nchunk; ++c) {
      float* u_c = u + (size_t)c*ch_rows*NDM;
      k_rms<<<ch_rows, 128, 0, stream>>>(u_c, scal);
      k_mgemm<0,128,128><<<dim3(ch_rows/64, 4), 256, 0, stream>>>(
          u_c, WiT, xh, z, scal, nw_l);
      k_conv<<<ch_seq, 256, 0, stream>>>(xh, cw_l, cb_l);
      k_mgemm<1,256,64><<<dim3(ch_rows/64, 1), 256, 0, stream>>>(
          xh, WxT, dbl, nullptr, nullptr, nullptr);
      k_scan<<<ch_seq, 256, 0, stream>>>(dbl, z, xh, Wdt_l, bdt_l, Al_l, Dp_l);
      k_mgemm<2,256,128><<<dim3(ch_rows/64, 1), 256, 0, stream>>>(
          xh, WoT, u_c, nullptr, nullptr, nullptr);
    }
  }

  k_head <<<NSEQ, 128, 0, stream>>>(u, fnw, hw, hfb, y1);
  k_final<<<1, 64, 0, stream>>>(y1, Wh, bh, (float*)d_out);
}

// Round 5
// 1032.635 us; speedup vs baseline: 2.6304x; 1.1837x over previous
//
#include <hip/hip_runtime.h>
#include <hip/hip_bf16.h>
#include <cstdio>

typedef __hip_bfloat16 bf16;
typedef __attribute__((ext_vector_type(8))) short short8;   // 8 bf16 = 4 VGPR
typedef __attribute__((ext_vector_type(4))) short short4v;
typedef __attribute__((ext_vector_type(4))) float f32x4;

#define NB    32
#define NK    256
#define NDIN  512
#define NPROJ 64
#define NDM   128
#define NNL   3
#define NT    63
#define NDI   256
#define NSEQ  2048            // NB*NPROJ
#define NROW  (NSEQ*NT)       // 129024
#define LDP   136             // LDS K-stride in shorts (17 * 16B)

static __device__ __forceinline__ float b2f(bf16 v){ return __bfloat162float(v); }
static __device__ __forceinline__ bf16  f2b(float v){ return __float2bfloat16(v); }
static __device__ __forceinline__ unsigned short f2bs(float v){   // RNE f32->bf16 bits
  unsigned int u = __float_as_uint(v);
  return (unsigned short)((u + 0x7FFFu + ((u >> 16) & 1u)) >> 16);
}
static __device__ __forceinline__ float siluf(float x){ return x / (1.f + __expf(-x)); }
static __device__ __forceinline__ float softplusf(float x){
  float e = __expf(-fabsf(x));
  return fmaxf(x, 0.f) + __logf(1.f + e);
}

// ---------------------------------------------------------------------------
// 0) all-layer weight pre-transpose to K-major bf16 (one dispatch).
//    per layer: 512 blocks Wi (K=128,srcN=512), 128 blocks Wo (K=256,srcN=128),
//               64 blocks Wx (K=256,srcN=40, zero-padded to 64 cols).
__global__ __launch_bounds__(256) void k_tw_all(
    const float* __restrict__ Wi, const float* __restrict__ Wo,
    const float* __restrict__ Wx,
    unsigned short* __restrict__ WiT, unsigned short* __restrict__ WoT,
    unsigned short* __restrict__ WxT)
{
  int bx = blockIdx.x;
  int l = bx / 704, r = bx - l*704;
  const float* src; unsigned short* dst; int K, srcN, nvalid, n;
  if (r < 512)      { n = r;     src = Wi + (size_t)l*128*512; dst = WiT + (size_t)l*512*128; K=128; srcN=512; nvalid=512; }
  else if (r < 640) { n = r-512; src = Wo + (size_t)l*256*128; dst = WoT + (size_t)l*128*256; K=256; srcN=128; nvalid=128; }
  else              { n = r-640; src = Wx + (size_t)l*256*40;  dst = WxT + (size_t)l*64*256;  K=256; srcN=40;  nvalid=40; }
  for (int k = threadIdx.x; k < K; k += 256) {
    float v = (n < nvalid) ? src[(size_t)k*srcN + n] : 0.f;
    dst[(size_t)n*K + k] = f2bs(v);
  }
}

// ---------------------------------------------------------------------------
// 1) hp[n][k] = x[b,k,:] . W_proj[:,p] + b_proj[p]
__global__ void k_proj(const float* __restrict__ x, const float* __restrict__ Wp,
                       const float* __restrict__ bp, float* __restrict__ hp)
{
  int blk = blockIdx.x;            // b*256 + k
  int b = blk >> 8, k = blk & 255;
  __shared__ float xr[NDIN];
  for (int i = threadIdx.x; i < NDIN; i += 64)
    xr[i] = x[(size_t)blk*NDIN + i];
  __syncthreads();
  int p = threadIdx.x;
  float acc = bp[p];
  #pragma unroll 8
  for (int d = 0; d < NDIN; ++d)
    acc += xr[d] * Wp[d*NPROJ + p];
  hp[(size_t)(b*NPROJ + p)*NK + k] = acc;
}

// ---------------------------------------------------------------------------
// 2) u[n,t,m] = sum_j hp[n][t*4+j] * We[j][m] + be[m]
__global__ void k_embed(const float* __restrict__ hp, const float* __restrict__ We,
                        const float* __restrict__ be, float* __restrict__ u)
{
  int blk = blockIdx.x;            // n*63 + t
  int n = blk / NT, t = blk - n*NT;
  int m = threadIdx.x;
  const float* hr = hp + (size_t)n*NK + t*4;
  float acc = be[m];
  #pragma unroll
  for (int j = 0; j < 8; ++j)
    acc += hr[j] * We[j*NDM + m];
  u[(size_t)blk*NDM + m] = acc;
}

// ---------------------------------------------------------------------------
// 4) MFMA GEMM. BM=64, BN=128/64, 256 threads (4 waves 2x2), wave tile 32x(BN/2).
//    MODE 0: in_proj + FUSED RMSNORM: A = u(f32 s128); per-row rms computed
//            in-staging (shfl_xor width-32 butterfly — the 32 lanes of a row
//            chunk hold the whole 128-wide row); A_frag = u*rsqrt*nw -> bf16.
//            B = WiT[512][128]; C bf16 col<256 -> xh else z.           K=128
//    MODE 1: x_proj  : A = xh bf16 s256; B = WxT[64][256]; C f32 dbl.  K=256
//    MODE 2: out_proj: A = xh bf16 s256; B = WoT[128][256]; u += .     K=256
template<int MODE, int KTOT, int BN>
__global__ __launch_bounds__(256) void
k_mgemm(const void* __restrict__ Aptr, const unsigned short* __restrict__ WT,
        void* __restrict__ Cptr, void* __restrict__ Cptr2,
        const float* __restrict__ nw)
{
  constexpr int MJ = BN/32;
  __shared__ short As[64*LDP];
  __shared__ short Bs[BN*LDP];

  const int tid  = threadIdx.x;
  const int r0   = blockIdx.x * 64;
  const int n0   = (MODE == 0) ? blockIdx.y * 128 : 0;
  const int w    = tid >> 6;
  const int lane = tid & 63;
  const int l16  = lane & 15;
  const int quad = lane >> 4;
  const int WM   = (w >> 1) * 32;
  const int WN   = (w & 1) * (BN/2);

  f32x4 acc[2][MJ] = {};

  for (int kc = 0; kc < KTOT; kc += 128) {
    // ---- stage A (64 rows x 128 k) ----
    if (MODE == 0) {
      // fused rmsnorm: row r is held by the 32 lanes (tid&~31..+31) at j=r>>3
      float4 va[8]; float ss[8];
      const float4 nwv = *(const float4*)(nw + ((tid & 31) << 2));
      #pragma unroll
      for (int j = 0; j < 8; ++j) {
        int c = tid + j*256;
        int row = c >> 5, k4 = (c & 31) << 2;
        va[j] = *(const float4*)((const float*)Aptr + (size_t)(r0+row)*128 + k4);
        ss[j] = va[j].x*va[j].x + va[j].y*va[j].y + va[j].z*va[j].z + va[j].w*va[j].w;
      }
      #pragma unroll
      for (int j = 0; j < 8; ++j) {
        float s = ss[j];
        #pragma unroll
        for (int m = 16; m >= 1; m >>= 1) s += __shfl_xor(s, m, 32);
        float sc = rsqrtf(s*(1.f/128.f) + 1e-5f);
        int c = tid + j*256;
        int row = c >> 5, k4 = (c & 31) << 2;
        short4v o = { (short)f2bs(va[j].x*sc*nwv.x), (short)f2bs(va[j].y*sc*nwv.y),
                      (short)f2bs(va[j].z*sc*nwv.z), (short)f2bs(va[j].w*sc*nwv.w) };
        *(short4v*)&As[row*LDP + k4] = o;
      }
    } else {
      #pragma unroll
      for (int j = 0; j < 4; ++j) {
        int c   = tid + j*256;          // 16B chunk
        int row = c >> 4, k8 = (c & 15) << 3;
        short8 v = *(const short8*)((const unsigned short*)Aptr
                                    + (size_t)(r0+row)*256 + kc + k8);
        *(short8*)&As[row*LDP + k8] = v;
      }
    }
    // ---- stage B (BN rows x 128 k) from K-major WT ----
    #pragma unroll
    for (int j = 0; j < BN/16; ++j) {
      int c  = tid + j*256;
      int n  = c >> 4, k8 = (c & 15) << 3;
      short8 v = *(const short8*)(WT + (size_t)(n0+n)*KTOT + kc + k8);
      *(short8*)&Bs[n*LDP + k8] = v;
    }
    __syncthreads();

    #pragma unroll
    for (int ks = 0; ks < 4; ++ks) {
      short8 a[2], b[MJ];
      #pragma unroll
      for (int i = 0; i < 2; ++i)
        a[i] = *(const short8*)&As[(WM + i*16 + l16)*LDP + ks*32 + quad*8];
      #pragma unroll
      for (int j = 0; j < MJ; ++j)
        b[j] = *(const short8*)&Bs[(WN + j*16 + l16)*LDP + ks*32 + quad*8];
      #pragma unroll
      for (int i = 0; i < 2; ++i)
        #pragma unroll
        for (int j = 0; j < MJ; ++j)
          acc[i][j] = __builtin_amdgcn_mfma_f32_16x16x32_bf16(a[i], b[j], acc[i][j], 0, 0, 0);
    }
    __syncthreads();
  }

  // ---- epilogue ----
  #pragma unroll
  for (int i = 0; i < 2; ++i) {
    #pragma unroll
    for (int j = 0; j < MJ; ++j) {
      #pragma unroll
      for (int rr = 0; rr < 4; ++rr) {
        int row = r0 + WM + i*16 + quad*4 + rr;
        int col = n0 + WN + j*16 + l16;
        float v = acc[i][j][rr];
        if (MODE == 0) {
          if (col < 256) ((unsigned short*)Cptr )[(size_t)row*256 + col]       = f2bs(v);
          else           ((unsigned short*)Cptr2)[(size_t)row*256 + col - 256] = f2bs(v);
        } else if (MODE == 1) {
          if (col < 40) ((float*)Cptr)[(size_t)row*40 + col] = v;
        } else {
          ((float*)Cptr)[(size_t)row*128 + col] += v;
        }
      }
    }
  }
}

// ---------------------------------------------------------------------------
// 5) depthwise causal conv(4) + bias + silu, IN PLACE on xh (stride 256).
__global__ __launch_bounds__(256) void k_conv(bf16* __restrict__ xh,
                       const float* __restrict__ cw, const float* __restrict__ cb)
{
  int n = blockIdx.x, d = threadIdx.x;
  float w0 = cw[d*4+0], w1 = cw[d*4+1];
  float w2 = cw[d*4+2], w3 = cw[d*4+3];
  float bias = cb[d];
  float xm3 = 0.f, xm2 = 0.f, xm1 = 0.f;
  bf16* ptr = xh + (size_t)n*NT*256 + d;
  for (int t = 0; t < NT; ++t) {
    float xt = b2f(ptr[(size_t)t*256]);
    float a  = bias + w0*xm3 + w1*xm2 + w2*xm1 + w3*xt;
    ptr[(size_t)t*256] = f2b(siluf(a));
    xm3 = xm2; xm2 = xm1; xm1 = xt;
  }
}

// ---------------------------------------------------------------------------
// 6) fused dt_proj + softplus + selective scan + skip + silu(z) gating.
//    A = -exp(A_log) is, for this problem, exactly -(s+1) for s=0..15 —
//    verified at runtime (chain flag); then exp(delta*A[s]) = E^(s+1) with
//    E = exp(delta*A[0]) via a depth-4 multiply tree (15 muls replace 16 exps).
__global__ __launch_bounds__(256) void k_scan(const float* __restrict__ dbl,
                       const bf16* __restrict__ z, bf16* __restrict__ xh,
                       const float* __restrict__ Wdt, const float* __restrict__ bdt,
                       const float* __restrict__ Alog, const float* __restrict__ Dpp)
{
  int n = blockIdx.x, d = threadIdx.x;
  __shared__ float sd[NT][40];    // dt(8) | B(16) | C(16)
  for (int i = threadIdx.x; i < NT*40; i += 256)
    sd[i/40][i%40] = dbl[(size_t)n*NT*40 + i];
  __syncthreads();

  float wdt[8];
  #pragma unroll
  for (int r = 0; r < 8; ++r) wdt[r] = Wdt[r*256 + d];
  float bd = bdt[d];
  float Av[16];
  #pragma unroll
  for (int s = 0; s < 16; ++s) Av[s] = -__expf(Alog[d*16 + s]);
  float Av0 = Av[0];
  bool chain = true;
  #pragma unroll
  for (int s = 0; s < 16; ++s)
    chain = chain && (fabsf(Av[s] - (float)(s+1)*Av0) <= 1e-3f*(float)(s+1));
  float dp = Dpp[d];
  float h[16];
  #pragma unroll
  for (int s = 0; s < 16; ++s) h[s] = 0.f;

  const bf16* zsrc = z  + (size_t)n*NT*256 + d;
  bf16*       uio  = xh + (size_t)n*NT*256 + d;

  if (chain) {
    for (int t = 0; t < NT; ++t) {
      float dtv = bd;
      #pragma unroll
      for (int r = 0; r < 8; ++r) dtv += sd[t][r]*wdt[r];
      float delta = softplusf(dtv);
      float ut = b2f(uio[(size_t)t*256]);
      float du = delta*ut;
      float E = __expf(delta*Av0);
      float p[16];
      p[0]=E;        p[1]=p[0]*p[0];  p[2]=p[1]*p[0];  p[3]=p[1]*p[1];
      p[4]=p[3]*p[0];p[5]=p[3]*p[1];  p[6]=p[3]*p[2];  p[7]=p[3]*p[3];
      p[8]=p[7]*p[0];p[9]=p[7]*p[1];  p[10]=p[7]*p[2]; p[11]=p[7]*p[3];
      p[12]=p[7]*p[4];p[13]=p[7]*p[5];p[14]=p[7]*p[6]; p[15]=p[7]*p[7];
      float yt = 0.f;
      #pragma unroll
      for (int s = 0; s < 16; ++s) {
        h[s] = h[s]*p[s] + du*sd[t][8+s];
        yt  += h[s]*sd[t][24+s];
      }
      float zv = b2f(zsrc[(size_t)t*256]);
      float y  = (yt + ut*dp) * siluf(zv);
      uio[(size_t)t*256] = f2b(y);
    }
  } else {
    for (int t = 0; t < NT; ++t) {
      float dtv = bd;
      #pragma unroll
      for (int r = 0; r < 8; ++r) dtv += sd[t][r]*wdt[r];
      float delta = softplusf(dtv);
      float ut = b2f(uio[(size_t)t*256]);
      float du = delta*ut;
      float yt = 0.f;
      #pragma unroll
      for (int s = 0; s < 16; ++s) {
        float e = __expf(delta*Av[s]);
        h[s] = h[s]*e + du*sd[t][8+s];
        yt  += h[s]*sd[t][24+s];
      }
      float zv = b2f(zsrc[(size_t)t*256]);
      float y  = (yt + ut*dp) * siluf(zv);
      uio[(size_t)t*256] = f2b(y);
    }
  }
}

// ---------------------------------------------------------------------------
// 7) final rmsnorm + flat head
__global__ __launch_bounds__(128) void k_head(const float* __restrict__ u,
                       const float* __restrict__ fnw,
                       const float* __restrict__ hw, const float* __restrict__ hfb,
                       float* __restrict__ y1)
{
  int n = blockIdx.x, m = threadIdx.x;
  float fw = fnw[m];
  float accp = 0.f;
  __shared__ float ws[2];
  for (int t = 0; t < NT; ++t) {
    float v = u[((size_t)n*NT + t)*NDM + m];
    float s = v*v;
    #pragma unroll
    for (int o = 32; o > 0; o >>= 1) s += __shfl_down(s, o);
    if ((m & 63) == 0) ws[m >> 6] = s;
    __syncthreads();
    float tot = ws[0] + ws[1];
    __syncthreads();
    float sc = rsqrtf(tot * (1.f/NDM) + 1e-5f);
    accp += v*sc*fw*hw[t*NDM + m];
  }
  #pragma unroll
  for (int o = 32; o > 0; o >>= 1) accp += __shfl_down(accp, o);
  if ((m & 63) == 0) ws[m >> 6] = accp;
  __syncthreads();
  if (m == 0) y1[n] = ws[0] + ws[1] + hfb[0];
}

// ---------------------------------------------------------------------------
// 8) out[b,c] = sum_p y1[b*64+p]*Wh[p,c] + bh[c].
__global__ __launch_bounds__(64) void k_final(const float* __restrict__ y1,
                        const float* __restrict__ Wh,
                        const float* __restrict__ bh, float* __restrict__ out)
{
  int t = threadIdx.x;
  int b = t >> 1, c = t & 1;
  float acc = bh[c];
  #pragma unroll 8
  for (int p = 0; p < 64; ++p) acc += y1[b*64 + p]*Wh[p*2 + c];
  out[b*2 + c] = acc;
}

// ---------------------------------------------------------------------------
extern "C" void kernel_launch(void* const* d_in, const int* in_sizes, int n_in,
                              void* d_out, int out_size, void* d_ws, size_t ws_size,
                              hipStream_t stream)
{
  const float* x    = (const float*)d_in[0];
  const float* Wp   = (const float*)d_in[1];
  const float* bp   = (const float*)d_in[2];
  const float* We   = (const float*)d_in[3];
  const float* be   = (const float*)d_in[4];
  const float* nrm  = (const float*)d_in[5];
  const float* Wi   = (const float*)d_in[6];
  const float* cw   = (const float*)d_in[7];
  const float* cb   = (const float*)d_in[8];
  const float* Wx   = (const float*)d_in[9];
  const float* Wdt  = (const float*)d_in[10];
  const float* bdt  = (const float*)d_in[11];
  const float* Alog = (const float*)d_in[12];
  const float* Dpp  = (const float*)d_in[13];
  const float* Wo   = (const float*)d_in[14];
  const float* fnw  = (const float*)d_in[15];
  const float* hw   = (const float*)d_in[16];
  const float* hfb  = (const float*)d_in[17];
  const float* Wh   = (const float*)d_in[18];
  const float* bh   = (const float*)d_in[19];

  // ---- workspace layout + adaptive chunking (ws = 256 MiB -> nchunk=1) ----
  const size_t wt_per_l = (size_t)512*128 + 128*256 + 64*256;   // shorts
  const size_t fixed_b = (size_t)NROW*NDM*4 + (size_t)NSEQ*NK*4 + NSEQ*4
                       + wt_per_l*2*NNL + 8192;
  const size_t per_seq = (size_t)NT*256*2*2 + (size_t)NT*40*4;
  int ch_seq = NSEQ;
  while (ch_seq > 128 && fixed_b + (size_t)ch_seq*per_seq + 2048 > ws_size)
    ch_seq >>= 1;
  const int nchunk  = NSEQ / ch_seq;
  const int ch_rows = ch_seq * NT;
  fprintf(stderr, "[mamba] ws_size=%zu ch_seq=%d nchunk=%d\n", ws_size, ch_seq, nchunk);

  char* pw = (char*)d_ws;
  float* u    = (float*)pw; pw += (size_t)NROW*NDM*4;
  float* hp   = (float*)pw; pw += (size_t)NSEQ*NK*4;
  float* y1   = (float*)pw; pw += (size_t)NSEQ*4;
  unsigned short* WiT = (unsigned short*)pw; pw += (size_t)NNL*512*128*2;
  unsigned short* WoT = (unsigned short*)pw; pw += (size_t)NNL*128*256*2;
  unsigned short* WxT = (unsigned short*)pw; pw += (size_t)NNL*64*256*2;
  float* dbl  = (float*)pw; pw += (size_t)ch_rows*40*4;
  bf16*  xh   = (bf16*)pw;  pw += (size_t)ch_rows*256*2;
  bf16*  z    = (bf16*)pw;  pw += (size_t)ch_rows*256*2;

  k_tw_all<<<3*704, 256, 0, stream>>>(Wi, Wo, Wx, WiT, WoT, WxT);
  k_proj <<<NB*NK,  64, 0, stream>>>(x, Wp, bp, hp);
  k_embed<<<NROW,  128, 0, stream>>>(hp, We, be, u);

  for (int l = 0; l < NNL; ++l) {
    const float* nw_l  = nrm  + (size_t)l*NDM;
    const float* cw_l  = cw   + (size_t)l*NDI*4;
    const float* cb_l  = cb   + (size_t)l*NDI;
    const float* Wdt_l = Wdt  + (size_t)l*8*NDI;
    const float* bdt_l = bdt  + (size_t)l*NDI;
    const float* Al_l  = Alog + (size_t)l*NDI*16;
    const float* Dp_l  = Dpp  + (size_t)l*NDI;
    const unsigned short* WiT_l = WiT + (size_t)l*512*128;
    const unsigned short* WoT_l = WoT + (size_t)l*128*256;
    const unsigned short* WxT_l = WxT + (size_t)l*64*256;

    for (int c = 0; c < nchunk; ++c) {
      float* u_c = u + (size_t)c*ch_rows*NDM;
      k_mgemm<0,128,128><<<dim3(ch_rows/64, 4), 256, 0, stream>>>(
          u_c, WiT_l, xh, z, nw_l);
      k_conv<<<ch_seq, 256, 0, stream>>>(xh, cw_l, cb_l);
      k_mgemm<1,256,64><<<dim3(ch_rows/64, 1), 256, 0, stream>>>(
          xh, WxT_l, dbl, nullptr, nullptr);
      k_scan<<<ch_seq, 256, 0, stream>>>(dbl, z, xh, Wdt_l, bdt_l, Al_l, Dp_l);
      k_mgemm<2,256,128><<<dim3(ch_rows/64, 1), 256, 0, stream>>>(
          xh, WoT_l, u_c, nullptr, nullptr);
    }
  }

  k_head <<<NSEQ, 128, 0, stream>>>(u, fnw, hw, hfb, y1);
  k_final<<<1, 64, 0, stream>>>(y1, Wh, bh, (float*)d_out);
}

// Round 7
// 842.170 us; speedup vs baseline: 3.2252x; 1.2262x over previous
//
#include <hip/hip_runtime.h>
#include <hip/hip_bf16.h>
#include <cstdio>

typedef __hip_bfloat16 bf16;
typedef __attribute__((ext_vector_type(8))) short short8;   // 8 bf16 = 4 VGPR
typedef __attribute__((ext_vector_type(4))) short short4v;
typedef __attribute__((ext_vector_type(4))) float f32x4;
typedef __attribute__((ext_vector_type(2))) float f32x2;

#define NB    32
#define NK    256
#define NDIN  512
#define NPROJ 64
#define NDM   128
#define NNL   3
#define NT    63
#define NDI   256
#define NSEQ  2048            // NB*NPROJ
#define NROW  (NSEQ*NT)       // 129024
#define LDP   136             // LDS K-stride in shorts (17 * 16B)

static __device__ __forceinline__ float b2f(bf16 v){ return __bfloat162float(v); }
static __device__ __forceinline__ bf16  f2b(float v){ return __float2bfloat16(v); }
static __device__ __forceinline__ unsigned short f2bs(float v){   // RNE f32->bf16 bits
  unsigned int u = __float_as_uint(v);
  return (unsigned short)((u + 0x7FFFu + ((u >> 16) & 1u)) >> 16);
}
// silu via v_rcp (1 slot) instead of IEEE div (~9 slots)
static __device__ __forceinline__ float siluf(float x){
  return x * __builtin_amdgcn_rcpf(1.f + __expf(-x));
}
static __device__ __forceinline__ float softplusf(float x){
  float e = __expf(-fabsf(x));
  return fmaxf(x, 0.f) + __logf(1.f + e);
}

// ---------------------------------------------------------------------------
// 0) all-layer weight pre-transpose to K-major bf16 (one dispatch).
__global__ __launch_bounds__(256) void k_tw_all(
    const float* __restrict__ Wi, const float* __restrict__ Wo,
    const float* __restrict__ Wx,
    unsigned short* __restrict__ WiT, unsigned short* __restrict__ WoT,
    unsigned short* __restrict__ WxT)
{
  int bx = blockIdx.x;
  int l = bx / 704, r = bx - l*704;
  const float* src; unsigned short* dst; int K, srcN, nvalid, n;
  if (r < 512)      { n = r;     src = Wi + (size_t)l*128*512; dst = WiT + (size_t)l*512*128; K=128; srcN=512; nvalid=512; }
  else if (r < 640) { n = r-512; src = Wo + (size_t)l*256*128; dst = WoT + (size_t)l*128*256; K=256; srcN=128; nvalid=128; }
  else              { n = r-640; src = Wx + (size_t)l*256*40;  dst = WxT + (size_t)l*64*256;  K=256; srcN=40;  nvalid=40; }
  for (int k = threadIdx.x; k < K; k += 256) {
    float v = (n < nvalid) ? src[(size_t)k*srcN + n] : 0.f;
    dst[(size_t)n*K + k] = f2bs(v);
  }
}

// ---------------------------------------------------------------------------
// 1) hp[n][k] = x[b,k,:] . W_proj[:,p] + b_proj[p]
__global__ void k_proj(const float* __restrict__ x, const float* __restrict__ Wp,
                       const float* __restrict__ bp, float* __restrict__ hp)
{
  int blk = blockIdx.x;            // b*256 + k
  int b = blk >> 8, k = blk & 255;
  __shared__ float xr[NDIN];
  for (int i = threadIdx.x; i < NDIN; i += 64)
    xr[i] = x[(size_t)blk*NDIN + i];
  __syncthreads();
  int p = threadIdx.x;
  float acc = bp[p];
  #pragma unroll 8
  for (int d = 0; d < NDIN; ++d)
    acc += xr[d] * Wp[d*NPROJ + p];
  hp[(size_t)(b*NPROJ + p)*NK + k] = acc;
}

// ---------------------------------------------------------------------------
// 2) u[n,t,m] = sum_j hp[n][t*4+j] * We[j][m] + be[m]
__global__ void k_embed(const float* __restrict__ hp, const float* __restrict__ We,
                        const float* __restrict__ be, float* __restrict__ u)
{
  int blk = blockIdx.x;            // n*63 + t
  int n = blk / NT, t = blk - n*NT;
  int m = threadIdx.x;
  const float* hr = hp + (size_t)n*NK + t*4;
  float acc = be[m];
  #pragma unroll
  for (int j = 0; j < 8; ++j)
    acc += hr[j] * We[j*NDM + m];
  u[(size_t)blk*NDM + m] = acc;
}

// ---------------------------------------------------------------------------
// 4) MFMA GEMM. BM=64, BN=128/64, 256 threads (4 waves 2x2), wave tile 32x(BN/2).
//    MODE 0: in_proj + fused rmsnorm (shfl_xor width-32 butterfly in A-staging).
//    MODE 1: x_proj. MODE 2: out_proj with u += epilogue.
template<int MODE, int KTOT, int BN>
__global__ __launch_bounds__(256) void
k_mgemm(const void* __restrict__ Aptr, const unsigned short* __restrict__ WT,
        void* __restrict__ Cptr, void* __restrict__ Cptr2,
        const float* __restrict__ nw)
{
  constexpr int MJ = BN/32;
  __shared__ short As[64*LDP];
  __shared__ short Bs[BN*LDP];

  const int tid  = threadIdx.x;
  const int r0   = blockIdx.x * 64;
  const int n0   = (MODE == 0) ? blockIdx.y * 128 : 0;
  const int w    = tid >> 6;
  const int lane = tid & 63;
  const int l16  = lane & 15;
  const int quad = lane >> 4;
  const int WM   = (w >> 1) * 32;
  const int WN   = (w & 1) * (BN/2);

  f32x4 acc[2][MJ] = {};

  for (int kc = 0; kc < KTOT; kc += 128) {
    // ---- stage A (64 rows x 128 k) ----
    if (MODE == 0) {
      float4 va[8]; float ss[8];
      const float4 nwv = *(const float4*)(nw + ((tid & 31) << 2));
      #pragma unroll
      for (int j = 0; j < 8; ++j) {
        int c = tid + j*256;
        int row = c >> 5, k4 = (c & 31) << 2;
        va[j] = *(const float4*)((const float*)Aptr + (size_t)(r0+row)*128 + k4);
        ss[j] = va[j].x*va[j].x + va[j].y*va[j].y + va[j].z*va[j].z + va[j].w*va[j].w;
      }
      #pragma unroll
      for (int j = 0; j < 8; ++j) {
        float s = ss[j];
        #pragma unroll
        for (int m = 16; m >= 1; m >>= 1) s += __shfl_xor(s, m, 32);
        float sc = rsqrtf(s*(1.f/128.f) + 1e-5f);
        int c = tid + j*256;
        int row = c >> 5, k4 = (c & 31) << 2;
        short4v o = { (short)f2bs(va[j].x*sc*nwv.x), (short)f2bs(va[j].y*sc*nwv.y),
                      (short)f2bs(va[j].z*sc*nwv.z), (short)f2bs(va[j].w*sc*nwv.w) };
        *(short4v*)&As[row*LDP + k4] = o;
      }
    } else {
      #pragma unroll
      for (int j = 0; j < 4; ++j) {
        int c   = tid + j*256;          // 16B chunk
        int row = c >> 4, k8 = (c & 15) << 3;
        short8 v = *(const short8*)((const unsigned short*)Aptr
                                    + (size_t)(r0+row)*256 + kc + k8);
        *(short8*)&As[row*LDP + k8] = v;
      }
    }
    // ---- stage B (BN rows x 128 k) from K-major WT ----
    #pragma unroll
    for (int j = 0; j < BN/16; ++j) {
      int c  = tid + j*256;
      int n  = c >> 4, k8 = (c & 15) << 3;
      short8 v = *(const short8*)(WT + (size_t)(n0+n)*KTOT + kc + k8);
      *(short8*)&Bs[n*LDP + k8] = v;
    }
    __syncthreads();

    #pragma unroll
    for (int ks = 0; ks < 4; ++ks) {
      short8 a[2], b[MJ];
      #pragma unroll
      for (int i = 0; i < 2; ++i)
        a[i] = *(const short8*)&As[(WM + i*16 + l16)*LDP + ks*32 + quad*8];
      #pragma unroll
      for (int j = 0; j < MJ; ++j)
        b[j] = *(const short8*)&Bs[(WN + j*16 + l16)*LDP + ks*32 + quad*8];
      #pragma unroll
      for (int i = 0; i < 2; ++i)
        #pragma unroll
        for (int j = 0; j < MJ; ++j)
          acc[i][j] = __builtin_amdgcn_mfma_f32_16x16x32_bf16(a[i], b[j], acc[i][j], 0, 0, 0);
    }
    __syncthreads();
  }

  // ---- epilogue ----
  #pragma unroll
  for (int i = 0; i < 2; ++i) {
    #pragma unroll
    for (int j = 0; j < MJ; ++j) {
      #pragma unroll
      for (int rr = 0; rr < 4; ++rr) {
        int row = r0 + WM + i*16 + quad*4 + rr;
        int col = n0 + WN + j*16 + l16;
        float v = acc[i][j][rr];
        if (MODE == 0) {
          if (col < 256) ((unsigned short*)Cptr )[(size_t)row*256 + col]       = f2bs(v);
          else           ((unsigned short*)Cptr2)[(size_t)row*256 + col - 256] = f2bs(v);
        } else if (MODE == 1) {
          if (col < 40) ((float*)Cptr)[(size_t)row*40 + col] = v;
        } else {
          ((float*)Cptr)[(size_t)row*128 + col] += v;
        }
      }
    }
  }
}

// ---------------------------------------------------------------------------
// 5) depthwise causal conv(4) + bias + silu, IN PLACE on xh (stride 256).
__global__ __launch_bounds__(256) void k_conv(bf16* __restrict__ xh,
                       const float* __restrict__ cw, const float* __restrict__ cb)
{
  int n = blockIdx.x, d = threadIdx.x;
  float w0 = cw[d*4+0], w1 = cw[d*4+1];
  float w2 = cw[d*4+2], w3 = cw[d*4+3];
  float bias = cb[d];
  float xm3 = 0.f, xm2 = 0.f, xm1 = 0.f;
  bf16* ptr = xh + (size_t)n*NT*256 + d;
  for (int t = 0; t < NT; ++t) {
    float xt = b2f(ptr[(size_t)t*256]);
    float a  = bias + w0*xm3 + w1*xm2 + w2*xm1 + w3*xt;
    ptr[(size_t)t*256] = f2b(siluf(a));
    xm3 = xm2; xm2 = xm1; xm1 = xt;
  }
}

// ---------------------------------------------------------------------------
// 6) fused dt_proj + softplus + selective scan + skip + silu(z) gating.
//    Fast path (runtime-verified): A[s] = -(s+1) exactly =>
//      E = exp(delta*A[0]) = exp(-softplus(dtv)) = sigmoid(-dtv);
//      delta = max(dtv,0) - log(rcp(1+exp(-|dtv|)));
//      powers E^(s+1) via packed chain; h/y updates in float2 (v_pk_fma).
__global__ __launch_bounds__(256) void k_scan(const float* __restrict__ dbl,
                       const bf16* __restrict__ z, bf16* __restrict__ xh,
                       const float* __restrict__ Wdt, const float* __restrict__ bdt,
                       const float* __restrict__ Alog, const float* __restrict__ Dpp)
{
  int n = blockIdx.x, d = threadIdx.x;
  __shared__ float sd[NT][40];    // dt(8) | B(16) | C(16)
  for (int i = threadIdx.x; i < NT*40; i += 256)
    sd[i/40][i%40] = dbl[(size_t)n*NT*40 + i];
  __syncthreads();

  float bd = bdt[d];
  float Av[16];
  #pragma unroll
  for (int s = 0; s < 16; ++s) Av[s] = -__expf(Alog[d*16 + s]);
  float Av0 = Av[0];
  bool chain = fabsf(Av0 + 1.f) <= 1e-3f;
  #pragma unroll
  for (int s = 0; s < 16; ++s)
    chain = chain && (fabsf(Av[s] - (float)(s+1)*Av0) <= 1e-3f*(float)(s+1));
  float dp = Dpp[d];

  const bf16* zsrc = z  + (size_t)n*NT*256 + d;
  bf16*       uio  = xh + (size_t)n*NT*256 + d;

  if (chain) {
    f32x2 wdt2[4];
    #pragma unroll
    for (int r = 0; r < 4; ++r) {
      f32x2 wv; wv.x = Wdt[(2*r)*256 + d]; wv.y = Wdt[(2*r+1)*256 + d];
      wdt2[r] = wv;
    }
    f32x2 h2[8];
    #pragma unroll
    for (int s = 0; s < 8; ++s) { h2[s].x = 0.f; h2[s].y = 0.f; }

    for (int t = 0; t < NT; ++t) {
      const f32x2* sdt = (const f32x2*)&sd[t][0];
      f32x2 a2; a2.x = bd; a2.y = 0.f;
      #pragma unroll
      for (int r = 0; r < 4; ++r) a2 += sdt[r]*wdt2[r];
      float dtv = a2.x + a2.y;
      // E = sigmoid(-dtv), delta = softplus(dtv), branchless & overflow-safe
      float q  = __expf(-fabsf(dtv));
      float r1 = __builtin_amdgcn_rcpf(1.f + q);
      float E  = dtv > 0.f ? q*r1 : r1;
      float delta = fmaxf(dtv, 0.f) - __logf(r1);
      float E2 = E*E;
      f32x2 ee; ee.x = E2; ee.y = E2;
      f32x2 p2[8];
      p2[0].x = E; p2[0].y = E2;
      #pragma unroll
      for (int s = 1; s < 8; ++s) p2[s] = p2[s-1]*ee;

      float ut = b2f(uio[(size_t)t*256]);
      float du = delta*ut;
      f32x2 du2; du2.x = du; du2.y = du;
      const f32x2* B2 = (const f32x2*)&sd[t][8];
      const f32x2* C2 = (const f32x2*)&sd[t][24];
      f32x2 yt2; yt2.x = 0.f; yt2.y = 0.f;
      #pragma unroll
      for (int s = 0; s < 8; ++s) {
        h2[s] = h2[s]*p2[s] + du2*B2[s];
        yt2  += h2[s]*C2[s];
      }
      float yt = yt2.x + yt2.y;
      float zv = b2f(zsrc[(size_t)t*256]);
      float y  = (yt + ut*dp) * siluf(zv);
      uio[(size_t)t*256] = f2b(y);
    }
  } else {
    float wdt[8];
    #pragma unroll
    for (int r = 0; r < 8; ++r) wdt[r] = Wdt[r*256 + d];
    float h[16];
    #pragma unroll
    for (int s = 0; s < 16; ++s) h[s] = 0.f;
    for (int t = 0; t < NT; ++t) {
      float dtv = bd;
      #pragma unroll
      for (int r = 0; r < 8; ++r) dtv += sd[t][r]*wdt[r];
      float delta = softplusf(dtv);
      float ut = b2f(uio[(size_t)t*256]);
      float du = delta*ut;
      float yt = 0.f;
      #pragma unroll
      for (int s = 0; s < 16; ++s) {
        float e = __expf(delta*Av[s]);
        h[s] = h[s]*e + du*sd[t][8+s];
        yt  += h[s]*sd[t][24+s];
      }
      float zv = b2f(zsrc[(size_t)t*256]);
      float y  = (yt + ut*dp) * siluf(zv);
      uio[(size_t)t*256] = f2b(y);
    }
  }
}

// ---------------------------------------------------------------------------
// 7) final rmsnorm + flat head. One wave per (n,t) row, no in-loop barriers:
//    4 waves/block (256 threads!) stride over t; 64 lanes x 2 floats = 128 row.
__global__ __launch_bounds__(256) void k_head(const float* __restrict__ u,
                       const float* __restrict__ fnw,
                       const float* __restrict__ hw, const float* __restrict__ hfb,
                       float* __restrict__ y1)
{
  int n = blockIdx.x;
  int w = threadIdx.x >> 6, lane = threadIdx.x & 63;
  const float2 fw = *(const float2*)&fnw[lane*2];
  float acc = 0.f;
  for (int t = w; t < NT; t += 4) {
    const float2 v  = *(const float2*)&u[((size_t)n*NT + t)*NDM + lane*2];
    const float2 hv = *(const float2*)&hw[t*NDM + lane*2];
    float ss = v.x*v.x + v.y*v.y;
    #pragma unroll
    for (int o = 32; o >= 1; o >>= 1) ss += __shfl_xor(ss, o);
    float sc = rsqrtf(ss*(1.f/128.f) + 1e-5f);
    acc += (v.x*fw.x*hv.x + v.y*fw.y*hv.y)*sc;
  }
  #pragma unroll
  for (int o = 32; o >= 1; o >>= 1) acc += __shfl_xor(acc, o);
  __shared__ float ws[4];
  if (lane == 0) ws[w] = acc;
  __syncthreads();
  if (threadIdx.x == 0) y1[n] = ws[0] + ws[1] + ws[2] + ws[3] + hfb[0];
}

// ---------------------------------------------------------------------------
// 8) out[b,c] = sum_p y1[b*64+p]*Wh[p,c] + bh[c].
__global__ __launch_bounds__(64) void k_final(const float* __restrict__ y1,
                        const float* __restrict__ Wh,
                        const float* __restrict__ bh, float* __restrict__ out)
{
  int t = threadIdx.x;
  int b = t >> 1, c = t & 1;
  float acc = bh[c];
  #pragma unroll 8
  for (int p = 0; p < 64; ++p) acc += y1[b*64 + p]*Wh[p*2 + c];
  out[b*2 + c] = acc;
}

// ---------------------------------------------------------------------------
extern "C" void kernel_launch(void* const* d_in, const int* in_sizes, int n_in,
                              void* d_out, int out_size, void* d_ws, size_t ws_size,
                              hipStream_t stream)
{
  const float* x    = (const float*)d_in[0];
  const float* Wp   = (const float*)d_in[1];
  const float* bp   = (const float*)d_in[2];
  const float* We   = (const float*)d_in[3];
  const float* be   = (const float*)d_in[4];
  const float* nrm  = (const float*)d_in[5];
  const float* Wi   = (const float*)d_in[6];
  const float* cw   = (const float*)d_in[7];
  const float* cb   = (const float*)d_in[8];
  const float* Wx   = (const float*)d_in[9];
  const float* Wdt  = (const float*)d_in[10];
  const float* bdt  = (const float*)d_in[11];
  const float* Alog = (const float*)d_in[12];
  const float* Dpp  = (const float*)d_in[13];
  const float* Wo   = (const float*)d_in[14];
  const float* fnw  = (const float*)d_in[15];
  const float* hw   = (const float*)d_in[16];
  const float* hfb  = (const float*)d_in[17];
  const float* Wh   = (const float*)d_in[18];
  const float* bh   = (const float*)d_in[19];

  // ---- workspace layout + adaptive chunking (ws = 256 MiB -> nchunk=1) ----
  const size_t wt_per_l = (size_t)512*128 + 128*256 + 64*256;   // shorts
  const size_t fixed_b = (size_t)NROW*NDM*4 + (size_t)NSEQ*NK*4 + NSEQ*4
                       + wt_per_l*2*NNL + 8192;
  const size_t per_seq = (size_t)NT*256*2*2 + (size_t)NT*40*4;
  int ch_seq = NSEQ;
  while (ch_seq > 128 && fixed_b + (size_t)ch_seq*per_seq + 2048 > ws_size)
    ch_seq >>= 1;
  const int nchunk  = NSEQ / ch_seq;
  const int ch_rows = ch_seq * NT;
  fprintf(stderr, "[mamba] ws_size=%zu ch_seq=%d nchunk=%d\n", ws_size, ch_seq, nchunk);

  char* pw = (char*)d_ws;
  float* u    = (float*)pw; pw += (size_t)NROW*NDM*4;
  float* hp   = (float*)pw; pw += (size_t)NSEQ*NK*4;
  float* y1   = (float*)pw; pw += (size_t)NSEQ*4;
  unsigned short* WiT = (unsigned short*)pw; pw += (size_t)NNL*512*128*2;
  unsigned short* WoT = (unsigned short*)pw; pw += (size_t)NNL*128*256*2;
  unsigned short* WxT = (unsigned short*)pw; pw += (size_t)NNL*64*256*2;
  float* dbl  = (float*)pw; pw += (size_t)ch_rows*40*4;
  bf16*  xh   = (bf16*)pw;  pw += (size_t)ch_rows*256*2;
  bf16*  z    = (bf16*)pw;  pw += (size_t)ch_rows*256*2;

  k_tw_all<<<3*704, 256, 0, stream>>>(Wi, Wo, Wx, WiT, WoT, WxT);
  k_proj <<<NB*NK,  64, 0, stream>>>(x, Wp, bp, hp);
  k_embed<<<NROW,  128, 0, stream>>>(hp, We, be, u);

  for (int l = 0; l < NNL; ++l) {
    const float* nw_l  = nrm  + (size_t)l*NDM;
    const float* cw_l  = cw   + (size_t)l*NDI*4;
    const float* cb_l  = cb   + (size_t)l*NDI;
    const float* Wdt_l = Wdt  + (size_t)l*8*NDI;
    const float* bdt_l = bdt  + (size_t)l*NDI;
    const float* Al_l  = Alog + (size_t)l*NDI*16;
    const float* Dp_l  = Dpp  + (size_t)l*NDI;
    const unsigned short* WiT_l = WiT + (size_t)l*512*128;
    const unsigned short* WoT_l = WoT + (size_t)l*128*256;
    const unsigned short* WxT_l = WxT + (size_t)l*64*256;

    for (int c = 0; c < nchunk; ++c) {
      float* u_c = u + (size_t)c*ch_rows*NDM;
      k_mgemm<0,128,128><<<dim3(ch_rows/64, 4), 256, 0, stream>>>(
          u_c, WiT_l, xh, z, nw_l);
      k_conv<<<ch_seq, 256, 0, stream>>>(xh, cw_l, cb_l);
      k_mgemm<1,256,64><<<dim3(ch_rows/64, 1), 256, 0, stream>>>(
          xh, WxT_l, dbl, nullptr, nullptr);
      k_scan<<<ch_seq, 256, 0, stream>>>(dbl, z, xh, Wdt_l, bdt_l, Al_l, Dp_l);
      k_mgemm<2,256,128><<<dim3(ch_rows/64, 1), 256, 0, stream>>>(
          xh, WoT_l, u_c, nullptr, nullptr);
    }
  }

  k_head <<<NSEQ, 256, 0, stream>>>(u, fnw, hw, hfb, y1);
  k_final<<<1, 64, 0, stream>>>(y1, Wh, bh, (float*)d_out);
}

// Round 8
// 744.146 us; speedup vs baseline: 3.6501x; 1.1317x over previous
//
#include <hip/hip_runtime.h>
#include <hip/hip_bf16.h>
#include <cstdio>

typedef __hip_bfloat16 bf16;
typedef __attribute__((ext_vector_type(8))) short short8;   // 8 bf16 = 4 VGPR
typedef __attribute__((ext_vector_type(4))) short short4v;
typedef __attribute__((ext_vector_type(4))) float f32x4;
typedef __attribute__((ext_vector_type(2))) float f32x2;

#define NB    32
#define NK    256
#define NDIN  512
#define NPROJ 64
#define NDM   128
#define NNL   3
#define NT    63
#define NDI   256
#define NSEQ  2048            // NB*NPROJ
#define NROW  (NSEQ*NT)       // 129024
#define LDP   136             // LDS K-stride in shorts (17 * 16B)

static __device__ __forceinline__ float b2f(bf16 v){ return __bfloat162float(v); }
static __device__ __forceinline__ bf16  f2b(float v){ return __float2bfloat16(v); }
static __device__ __forceinline__ unsigned short f2bs(float v){   // RNE f32->bf16 bits
  unsigned int u = __float_as_uint(v);
  return (unsigned short)((u + 0x7FFFu + ((u >> 16) & 1u)) >> 16);
}
static __device__ __forceinline__ float bs2f(unsigned short b){   // bf16 bits -> f32
  return __uint_as_float(((unsigned int)b) << 16);
}
// silu via v_rcp (1 slot) instead of IEEE div (~9 slots)
static __device__ __forceinline__ float siluf(float x){
  return x * __builtin_amdgcn_rcpf(1.f + __expf(-x));
}
static __device__ __forceinline__ float softplusf(float x){
  float e = __expf(-fabsf(x));
  return fmaxf(x, 0.f) + __logf(1.f + e);
}

// ---------------------------------------------------------------------------
// 0) all-layer weight pre-transpose to K-major bf16 (one dispatch).
__global__ __launch_bounds__(256) void k_tw_all(
    const float* __restrict__ Wi, const float* __restrict__ Wo,
    const float* __restrict__ Wx,
    unsigned short* __restrict__ WiT, unsigned short* __restrict__ WoT,
    unsigned short* __restrict__ WxT)
{
  int bx = blockIdx.x;
  int l = bx / 704, r = bx - l*704;
  const float* src; unsigned short* dst; int K, srcN, nvalid, n;
  if (r < 512)      { n = r;     src = Wi + (size_t)l*128*512; dst = WiT + (size_t)l*512*128; K=128; srcN=512; nvalid=512; }
  else if (r < 640) { n = r-512; src = Wo + (size_t)l*256*128; dst = WoT + (size_t)l*128*256; K=256; srcN=128; nvalid=128; }
  else              { n = r-640; src = Wx + (size_t)l*256*40;  dst = WxT + (size_t)l*64*256;  K=256; srcN=40;  nvalid=40; }
  for (int k = threadIdx.x; k < K; k += 256) {
    float v = (n < nvalid) ? src[(size_t)k*srcN + n] : 0.f;
    dst[(size_t)n*K + k] = f2bs(v);
  }
}

// ---------------------------------------------------------------------------
// 1) hp[n][k] = x[b,k,:] . W_proj[:,p] + b_proj[p]
__global__ void k_proj(const float* __restrict__ x, const float* __restrict__ Wp,
                       const float* __restrict__ bp, float* __restrict__ hp)
{
  int blk = blockIdx.x;            // b*256 + k
  int b = blk >> 8, k = blk & 255;
  __shared__ float xr[NDIN];
  for (int i = threadIdx.x; i < NDIN; i += 64)
    xr[i] = x[(size_t)blk*NDIN + i];
  __syncthreads();
  int p = threadIdx.x;
  float acc = bp[p];
  #pragma unroll 8
  for (int d = 0; d < NDIN; ++d)
    acc += xr[d] * Wp[d*NPROJ + p];
  hp[(size_t)(b*NPROJ + p)*NK + k] = acc;
}

// ---------------------------------------------------------------------------
// 2) u[n,t,m] (bf16) = sum_j hp[n][t*4+j] * We[j][m] + be[m]
__global__ void k_embed(const float* __restrict__ hp, const float* __restrict__ We,
                        const float* __restrict__ be, unsigned short* __restrict__ u)
{
  int blk = blockIdx.x;            // n*63 + t
  int n = blk / NT, t = blk - n*NT;
  int m = threadIdx.x;
  const float* hr = hp + (size_t)n*NK + t*4;
  float acc = be[m];
  #pragma unroll
  for (int j = 0; j < 8; ++j)
    acc += hr[j] * We[j*NDM + m];
  u[(size_t)blk*NDM + m] = f2bs(acc);
}

// ---------------------------------------------------------------------------
// 3) in_proj + fused rmsnorm. A (u bf16, 64 rows x K=128) staged ONCE into
//    LDS (rms via shfl_xor width-16 butterfly: 16 lanes x 8 elems = row).
//    Then loop the 4 B-tiles (512 N-cols) in-kernel: A fetched 1x not 4x.
__global__ __launch_bounds__(256) void k_inproj(
    const unsigned short* __restrict__ ub, const unsigned short* __restrict__ WT,
    unsigned short* __restrict__ xh, unsigned short* __restrict__ zb,
    const float* __restrict__ nw)
{
  __shared__ short As[64*LDP];
  __shared__ short Bs[128*LDP];
  const int tid  = threadIdx.x;
  const int r0   = blockIdx.x * 64;
  const int w    = tid >> 6;
  const int lane = tid & 63;
  const int l16  = lane & 15;
  const int quad = lane >> 4;
  const int WM   = (w >> 1) * 32;
  const int WN   = (w & 1) * 64;

  // ---- stage A once (64 rows x 128 k) with fused rmsnorm ----
  #pragma unroll
  for (int j = 0; j < 4; ++j) {
    int c = tid + j*256;
    int row = c >> 4, k8 = (c & 15) << 3;
    short8 vb = *(const short8*)&ub[(size_t)(r0+row)*128 + k8];
    float f[8];
    #pragma unroll
    for (int i = 0; i < 8; ++i) f[i] = bs2f((unsigned short)vb[i]);
    float ss = 0.f;
    #pragma unroll
    for (int i = 0; i < 8; ++i) ss += f[i]*f[i];
    #pragma unroll
    for (int m = 8; m >= 1; m >>= 1) ss += __shfl_xor(ss, m, 16);
    float sc = rsqrtf(ss*(1.f/128.f) + 1e-5f);
    const float4 nw0 = *(const float4*)&nw[k8];
    const float4 nw1 = *(const float4*)&nw[k8+4];
    short8 o;
    o[0] = (short)f2bs(f[0]*sc*nw0.x); o[1] = (short)f2bs(f[1]*sc*nw0.y);
    o[2] = (short)f2bs(f[2]*sc*nw0.z); o[3] = (short)f2bs(f[3]*sc*nw0.w);
    o[4] = (short)f2bs(f[4]*sc*nw1.x); o[5] = (short)f2bs(f[5]*sc*nw1.y);
    o[6] = (short)f2bs(f[6]*sc*nw1.z); o[7] = (short)f2bs(f[7]*sc*nw1.w);
    *(short8*)&As[row*LDP + k8] = o;
  }

  for (int ny = 0; ny < 4; ++ny) {
    if (ny) __syncthreads();           // all MFMA reads of Bs done
    // ---- stage B tile (128 n-rows x 128 k) ----
    #pragma unroll
    for (int j = 0; j < 8; ++j) {
      int c = tid + j*256;
      int n = c >> 4, k8 = (c & 15) << 3;
      *(short8*)&Bs[n*LDP + k8] =
          *(const short8*)&WT[(size_t)(ny*128 + n)*128 + k8];
    }
    __syncthreads();                   // Bs (and As on ny=0) visible

    f32x4 acc[2][4] = {};
    #pragma unroll
    for (int ks = 0; ks < 4; ++ks) {
      short8 a[2], b[4];
      #pragma unroll
      for (int i = 0; i < 2; ++i)
        a[i] = *(const short8*)&As[(WM + i*16 + l16)*LDP + ks*32 + quad*8];
      #pragma unroll
      for (int j = 0; j < 4; ++j)
        b[j] = *(const short8*)&Bs[(WN + j*16 + l16)*LDP + ks*32 + quad*8];
      #pragma unroll
      for (int i = 0; i < 2; ++i)
        #pragma unroll
        for (int j = 0; j < 4; ++j)
          acc[i][j] = __builtin_amdgcn_mfma_f32_16x16x32_bf16(a[i], b[j], acc[i][j], 0, 0, 0);
    }
    // ---- epilogue for this ny ----
    #pragma unroll
    for (int i = 0; i < 2; ++i) {
      #pragma unroll
      for (int j = 0; j < 4; ++j) {
        #pragma unroll
        for (int rr = 0; rr < 4; ++rr) {
          int row = r0 + WM + i*16 + quad*4 + rr;
          int col = ny*128 + WN + j*16 + l16;
          float v = acc[i][j][rr];
          if (col < 256) xh[(size_t)row*256 + col]       = f2bs(v);
          else           zb[(size_t)row*256 + col - 256] = f2bs(v);
        }
      }
    }
  }
}

// ---------------------------------------------------------------------------
// 4) MFMA GEMM (x_proj / out_proj). BM=64, 256 threads (4 waves 2x2).
//    MODE 1: x_proj  : A = xh bf16 s256; B = WxT[64][256]; C f32 dbl(s40).
//    MODE 2: out_proj: A = xh bf16 s256; B = WoT[128][256]; u(bf16) += .
template<int MODE, int KTOT, int BN>
__global__ __launch_bounds__(256) void
k_mgemm(const void* __restrict__ Aptr, const unsigned short* __restrict__ WT,
        void* __restrict__ Cptr)
{
  constexpr int MJ = BN/32;
  __shared__ short As[64*LDP];
  __shared__ short Bs[BN*LDP];

  const int tid  = threadIdx.x;
  const int r0   = blockIdx.x * 64;
  const int w    = tid >> 6;
  const int lane = tid & 63;
  const int l16  = lane & 15;
  const int quad = lane >> 4;
  const int WM   = (w >> 1) * 32;
  const int WN   = (w & 1) * (BN/2);

  f32x4 acc[2][MJ] = {};

  for (int kc = 0; kc < KTOT; kc += 128) {
    #pragma unroll
    for (int j = 0; j < 4; ++j) {
      int c   = tid + j*256;          // 16B chunk
      int row = c >> 4, k8 = (c & 15) << 3;
      short8 v = *(const short8*)((const unsigned short*)Aptr
                                  + (size_t)(r0+row)*256 + kc + k8);
      *(short8*)&As[row*LDP + k8] = v;
    }
    #pragma unroll
    for (int j = 0; j < BN/16; ++j) {
      int c  = tid + j*256;
      int n  = c >> 4, k8 = (c & 15) << 3;
      short8 v = *(const short8*)(WT + (size_t)n*KTOT + kc + k8);
      *(short8*)&Bs[n*LDP + k8] = v;
    }
    __syncthreads();

    #pragma unroll
    for (int ks = 0; ks < 4; ++ks) {
      short8 a[2], b[MJ];
      #pragma unroll
      for (int i = 0; i < 2; ++i)
        a[i] = *(const short8*)&As[(WM + i*16 + l16)*LDP + ks*32 + quad*8];
      #pragma unroll
      for (int j = 0; j < MJ; ++j)
        b[j] = *(const short8*)&Bs[(WN + j*16 + l16)*LDP + ks*32 + quad*8];
      #pragma unroll
      for (int i = 0; i < 2; ++i)
        #pragma unroll
        for (int j = 0; j < MJ; ++j)
          acc[i][j] = __builtin_amdgcn_mfma_f32_16x16x32_bf16(a[i], b[j], acc[i][j], 0, 0, 0);
    }
    __syncthreads();
  }

  // ---- epilogue ----
  #pragma unroll
  for (int i = 0; i < 2; ++i) {
    #pragma unroll
    for (int j = 0; j < MJ; ++j) {
      #pragma unroll
      for (int rr = 0; rr < 4; ++rr) {
        int row = r0 + WM + i*16 + quad*4 + rr;
        int col = WN + j*16 + l16;
        float v = acc[i][j][rr];
        if (MODE == 1) {
          if (col < 40) ((float*)Cptr)[(size_t)row*40 + col] = v;
        } else {
          unsigned short* p = (unsigned short*)Cptr + (size_t)row*128 + col;
          *p = f2bs(bs2f(*p) + v);
        }
      }
    }
  }
}

// ---------------------------------------------------------------------------
// 5) depthwise causal conv(4) + bias + silu, IN PLACE on xh (stride 256).
__global__ __launch_bounds__(256) void k_conv(bf16* __restrict__ xh,
                       const float* __restrict__ cw, const float* __restrict__ cb)
{
  int n = blockIdx.x, d = threadIdx.x;
  float w0 = cw[d*4+0], w1 = cw[d*4+1];
  float w2 = cw[d*4+2], w3 = cw[d*4+3];
  float bias = cb[d];
  float xm3 = 0.f, xm2 = 0.f, xm1 = 0.f;
  bf16* ptr = xh + (size_t)n*NT*256 + d;
  for (int t = 0; t < NT; ++t) {
    float xt = b2f(ptr[0]);
    float a  = bias + w0*xm3 + w1*xm2 + w2*xm1 + w3*xt;
    ptr[0] = f2b(siluf(a));
    ptr += 256;
    xm3 = xm2; xm2 = xm1; xm1 = xt;
  }
}

// ---------------------------------------------------------------------------
// 6) fused dt_proj + softplus + selective scan + skip + silu(z) gating.
//    Fast path (runtime-verified): A[s] = -(s+1) exactly =>
//      E = exp(delta*A[0]) = sigmoid(-dtv); delta = softplus(dtv) shared;
//      powers via packed chain; h/y in float2. u/z prefetched one step ahead.
__global__ __launch_bounds__(256) void k_scan(const float* __restrict__ dbl,
                       const bf16* __restrict__ z, bf16* __restrict__ xh,
                       const float* __restrict__ Wdt, const float* __restrict__ bdt,
                       const float* __restrict__ Alog, const float* __restrict__ Dpp)
{
  int n = blockIdx.x, d = threadIdx.x;
  __shared__ float sd[NT][40];    // dt(8) | B(16) | C(16)
  for (int i = threadIdx.x; i < NT*40; i += 256)
    sd[i/40][i%40] = dbl[(size_t)n*NT*40 + i];
  __syncthreads();

  float bd = bdt[d];
  float Av[16];
  #pragma unroll
  for (int s = 0; s < 16; ++s) Av[s] = -__expf(Alog[d*16 + s]);
  float Av0 = Av[0];
  bool chain = fabsf(Av0 + 1.f) <= 1e-3f;
  #pragma unroll
  for (int s = 0; s < 16; ++s)
    chain = chain && (fabsf(Av[s] - (float)(s+1)*Av0) <= 1e-3f*(float)(s+1));
  float dp = Dpp[d];

  const unsigned short* zp = (const unsigned short*)z + (size_t)n*NT*256 + d;
  unsigned short*       up = (unsigned short*)xh + (size_t)n*NT*256 + d;

  if (chain) {
    f32x2 wdt2[4];
    #pragma unroll
    for (int r = 0; r < 4; ++r) {
      f32x2 wv; wv.x = Wdt[(2*r)*256 + d]; wv.y = Wdt[(2*r+1)*256 + d];
      wdt2[r] = wv;
    }
    f32x2 h2[8];
    #pragma unroll
    for (int s = 0; s < 8; ++s) { h2[s].x = 0.f; h2[s].y = 0.f; }

    unsigned short ucur = up[0], zcur = zp[0];
    for (int t = 0; t < NT; ++t) {
      unsigned short unx = 0, znx = 0;
      if (t < NT-1) { unx = up[(t+1)*256]; znx = zp[(t+1)*256]; }
      const f32x2* sdt = (const f32x2*)&sd[t][0];
      f32x2 a2; a2.x = bd; a2.y = 0.f;
      #pragma unroll
      for (int r = 0; r < 4; ++r) a2 += sdt[r]*wdt2[r];
      float dtv = a2.x + a2.y;
      // E = sigmoid(-dtv), delta = softplus(dtv), branchless & overflow-safe
      float q  = __expf(-fabsf(dtv));
      float r1 = __builtin_amdgcn_rcpf(1.f + q);
      float E  = dtv > 0.f ? q*r1 : r1;
      float delta = fmaxf(dtv, 0.f) - __logf(r1);
      float E2 = E*E;
      f32x2 ee; ee.x = E2; ee.y = E2;
      f32x2 p2[8];
      p2[0].x = E; p2[0].y = E2;
      #pragma unroll
      for (int s = 1; s < 8; ++s) p2[s] = p2[s-1]*ee;

      float ut = bs2f(ucur);
      float du = delta*ut;
      f32x2 du2; du2.x = du; du2.y = du;
      const f32x2* B2 = (const f32x2*)&sd[t][8];
      const f32x2* C2 = (const f32x2*)&sd[t][24];
      f32x2 yt2; yt2.x = 0.f; yt2.y = 0.f;
      #pragma unroll
      for (int s = 0; s < 8; ++s) {
        h2[s] = h2[s]*p2[s] + du2*B2[s];
        yt2  += h2[s]*C2[s];
      }
      float yt = yt2.x + yt2.y;
      float zv = bs2f(zcur);
      float y  = (yt + ut*dp) * siluf(zv);
      up[t*256] = f2bs(y);
      ucur = unx; zcur = znx;
    }
  } else {
    float wdt[8];
    #pragma unroll
    for (int r = 0; r < 8; ++r) wdt[r] = Wdt[r*256 + d];
    float h[16];
    #pragma unroll
    for (int s = 0; s < 16; ++s) h[s] = 0.f;
    for (int t = 0; t < NT; ++t) {
      float dtv = bd;
      #pragma unroll
      for (int r = 0; r < 8; ++r) dtv += sd[t][r]*wdt[r];
      float delta = softplusf(dtv);
      float ut = bs2f(up[t*256]);
      float du = delta*ut;
      float yt = 0.f;
      #pragma unroll
      for (int s = 0; s < 16; ++s) {
        float e = __expf(delta*Av[s]);
        h[s] = h[s]*e + du*sd[t][8+s];
        yt  += h[s]*sd[t][24+s];
      }
      float zv = bs2f(zp[t*256]);
      float y  = (yt + ut*dp) * siluf(zv);
      up[t*256] = f2bs(y);
    }
  }
}

// ---------------------------------------------------------------------------
// 7) final rmsnorm + flat head. One wave per (n,t) row; u is bf16.
__global__ __launch_bounds__(256) void k_head(const unsigned short* __restrict__ u,
                       const float* __restrict__ fnw,
                       const float* __restrict__ hw, const float* __restrict__ hfb,
                       float* __restrict__ y1)
{
  int n = blockIdx.x;
  int w = threadIdx.x >> 6, lane = threadIdx.x & 63;
  const float2 fw = *(const float2*)&fnw[lane*2];
  float acc = 0.f;
  for (int t = w; t < NT; t += 4) {
    const ushort2 vb = *(const ushort2*)&u[((size_t)n*NT + t)*NDM + lane*2];
    float vx = bs2f(vb.x), vy = bs2f(vb.y);
    const float2 hv = *(const float2*)&hw[t*NDM + lane*2];
    float ss = vx*vx + vy*vy;
    #pragma unroll
    for (int o = 32; o >= 1; o >>= 1) ss += __shfl_xor(ss, o);
    float sc = rsqrtf(ss*(1.f/128.f) + 1e-5f);
    acc += (vx*fw.x*hv.x + vy*fw.y*hv.y)*sc;
  }
  #pragma unroll
  for (int o = 32; o >= 1; o >>= 1) acc += __shfl_xor(acc, o);
  __shared__ float ws[4];
  if (lane == 0) ws[w] = acc;
  __syncthreads();
  if (threadIdx.x == 0) y1[n] = ws[0] + ws[1] + ws[2] + ws[3] + hfb[0];
}

// ---------------------------------------------------------------------------
// 8) out[b,c] = sum_p y1[b*64+p]*Wh[p,c] + bh[c].
__global__ __launch_bounds__(64) void k_final(const float* __restrict__ y1,
                        const float* __restrict__ Wh,
                        const float* __restrict__ bh, float* __restrict__ out)
{
  int t = threadIdx.x;
  int b = t >> 1, c = t & 1;
  float acc = bh[c];
  #pragma unroll 8
  for (int p = 0; p < 64; ++p) acc += y1[b*64 + p]*Wh[p*2 + c];
  out[b*2 + c] = acc;
}

// ---------------------------------------------------------------------------
extern "C" void kernel_launch(void* const* d_in, const int* in_sizes, int n_in,
                              void* d_out, int out_size, void* d_ws, size_t ws_size,
                              hipStream_t stream)
{
  const float* x    = (const float*)d_in[0];
  const float* Wp   = (const float*)d_in[1];
  const float* bp   = (const float*)d_in[2];
  const float* We   = (const float*)d_in[3];
  const float* be   = (const float*)d_in[4];
  const float* nrm  = (const float*)d_in[5];
  const float* Wi   = (const float*)d_in[6];
  const float* cw   = (const float*)d_in[7];
  const float* cb   = (const float*)d_in[8];
  const float* Wx   = (const float*)d_in[9];
  const float* Wdt  = (const float*)d_in[10];
  const float* bdt  = (const float*)d_in[11];
  const float* Alog = (const float*)d_in[12];
  const float* Dpp  = (const float*)d_in[13];
  const float* Wo   = (const float*)d_in[14];
  const float* fnw  = (const float*)d_in[15];
  const float* hw   = (const float*)d_in[16];
  const float* hfb  = (const float*)d_in[17];
  const float* Wh   = (const float*)d_in[18];
  const float* bh   = (const float*)d_in[19];

  // ---- workspace layout + adaptive chunking (u now bf16) ----
  const size_t wt_per_l = (size_t)512*128 + 128*256 + 64*256;   // shorts
  const size_t fixed_b = (size_t)NROW*NDM*2 + (size_t)NSEQ*NK*4 + NSEQ*4
                       + wt_per_l*2*NNL + 8192;
  const size_t per_seq = (size_t)NT*256*2*2 + (size_t)NT*40*4;
  int ch_seq = NSEQ;
  while (ch_seq > 128 && fixed_b + (size_t)ch_seq*per_seq + 2048 > ws_size)
    ch_seq >>= 1;
  const int nchunk  = NSEQ / ch_seq;
  const int ch_rows = ch_seq * NT;
  fprintf(stderr, "[mamba] ws_size=%zu ch_seq=%d nchunk=%d\n", ws_size, ch_seq, nchunk);

  char* pw = (char*)d_ws;
  unsigned short* u = (unsigned short*)pw; pw += (size_t)NROW*NDM*2;
  float* hp   = (float*)pw; pw += (size_t)NSEQ*NK*4;
  float* y1   = (float*)pw; pw += (size_t)NSEQ*4;
  unsigned short* WiT = (unsigned short*)pw; pw += (size_t)NNL*512*128*2;
  unsigned short* WoT = (unsigned short*)pw; pw += (size_t)NNL*128*256*2;
  unsigned short* WxT = (unsigned short*)pw; pw += (size_t)NNL*64*256*2;
  float* dbl  = (float*)pw; pw += (size_t)ch_rows*40*4;
  bf16*  xh   = (bf16*)pw;  pw += (size_t)ch_rows*256*2;
  bf16*  z    = (bf16*)pw;  pw += (size_t)ch_rows*256*2;

  k_tw_all<<<3*704, 256, 0, stream>>>(Wi, Wo, Wx, WiT, WoT, WxT);
  k_proj <<<NB*NK,  64, 0, stream>>>(x, Wp, bp, hp);
  k_embed<<<NROW,  128, 0, stream>>>(hp, We, be, u);

  for (int l = 0; l < NNL; ++l) {
    const float* nw_l  = nrm  + (size_t)l*NDM;
    const float* cw_l  = cw   + (size_t)l*NDI*4;
    const float* cb_l  = cb   + (size_t)l*NDI;
    const float* Wdt_l = Wdt  + (size_t)l*8*NDI;
    const float* bdt_l = bdt  + (size_t)l*NDI;
    const float* Al_l  = Alog + (size_t)l*NDI*16;
    const float* Dp_l  = Dpp  + (size_t)l*NDI;
    const unsigned short* WiT_l = WiT + (size_t)l*512*128;
    const unsigned short* WoT_l = WoT + (size_t)l*128*256;
    const unsigned short* WxT_l = WxT + (size_t)l*64*256;

    for (int c = 0; c < nchunk; ++c) {
      unsigned short* u_c = u + (size_t)c*ch_rows*NDM;
      k_inproj<<<ch_rows/64, 256, 0, stream>>>(
          u_c, WiT_l, (unsigned short*)xh, (unsigned short*)z, nw_l);
      k_conv<<<ch_seq, 256, 0, stream>>>(xh, cw_l, cb_l);
      k_mgemm<1,256,64><<<ch_rows/64, 256, 0, stream>>>(xh, WxT_l, dbl);
      k_scan<<<ch_seq, 256, 0, stream>>>(dbl, z, xh, Wdt_l, bdt_l, Al_l, Dp_l);
      k_mgemm<2,256,128><<<ch_rows/64, 256, 0, stream>>>(xh, WoT_l, u_c);
    }
  }

  k_head <<<NSEQ, 256, 0, stream>>>(u, fnw, hw, hfb, y1);
  k_final<<<1, 64, 0, stream>>>(y1, Wh, bh, (float*)d_out);
}

// Round 9
// 736.118 us; speedup vs baseline: 3.6899x; 1.0109x over previous
//
#include <hip/hip_runtime.h>
#include <hip/hip_bf16.h>
#include <cstdio>

typedef __hip_bfloat16 bf16;
typedef __attribute__((ext_vector_type(8))) short short8;   // 8 bf16 = 4 VGPR
typedef __attribute__((ext_vector_type(4))) short short4v;
typedef __attribute__((ext_vector_type(4))) float f32x4;
typedef __attribute__((ext_vector_type(2))) float f32x2;

#define NB    32
#define NK    256
#define NDIN  512
#define NPROJ 64
#define NDM   128
#define NNL   3
#define NT    63
#define NDI   256
#define NSEQ  2048            // NB*NPROJ
#define NROW  (NSEQ*NT)       // 129024
#define LDP   136             // LDS K-stride in shorts (17 * 16B)

static __device__ __forceinline__ float b2f(bf16 v){ return __bfloat162float(v); }
static __device__ __forceinline__ bf16  f2b(float v){ return __float2bfloat16(v); }
static __device__ __forceinline__ unsigned short f2bs(float v){   // RNE f32->bf16 bits
  unsigned int u = __float_as_uint(v);
  return (unsigned short)((u + 0x7FFFu + ((u >> 16) & 1u)) >> 16);
}
static __device__ __forceinline__ float bs2f(unsigned short b){   // bf16 bits -> f32
  return __uint_as_float(((unsigned int)b) << 16);
}
// silu via v_rcp (1 slot) instead of IEEE div (~9 slots)
static __device__ __forceinline__ float siluf(float x){
  return x * __builtin_amdgcn_rcpf(1.f + __expf(-x));
}
static __device__ __forceinline__ float softplusf(float x){
  float e = __expf(-fabsf(x));
  return fmaxf(x, 0.f) + __logf(1.f + e);
}

// ---------------------------------------------------------------------------
// 0) all-layer weight pre-transpose to K-major bf16 (one dispatch).
__global__ __launch_bounds__(256) void k_tw_all(
    const float* __restrict__ Wi, const float* __restrict__ Wo,
    const float* __restrict__ Wx,
    unsigned short* __restrict__ WiT, unsigned short* __restrict__ WoT,
    unsigned short* __restrict__ WxT)
{
  int bx = blockIdx.x;
  int l = bx / 704, r = bx - l*704;
  const float* src; unsigned short* dst; int K, srcN, nvalid, n;
  if (r < 512)      { n = r;     src = Wi + (size_t)l*128*512; dst = WiT + (size_t)l*512*128; K=128; srcN=512; nvalid=512; }
  else if (r < 640) { n = r-512; src = Wo + (size_t)l*256*128; dst = WoT + (size_t)l*128*256; K=256; srcN=128; nvalid=128; }
  else              { n = r-640; src = Wx + (size_t)l*256*40;  dst = WxT + (size_t)l*64*256;  K=256; srcN=40;  nvalid=40; }
  for (int k = threadIdx.x; k < K; k += 256) {
    float v = (n < nvalid) ? src[(size_t)k*srcN + n] : 0.f;
    dst[(size_t)n*K + k] = f2bs(v);
  }
}

// ---------------------------------------------------------------------------
// 1) hp[n][k] = x[b,k,:] . W_proj[:,p] + b_proj[p]
//    4 k-positions per block: Wp read once per 4 outputs (L2 traffic /4).
__global__ __launch_bounds__(64) void k_proj(const float* __restrict__ x,
                       const float* __restrict__ Wp,
                       const float* __restrict__ bp, float* __restrict__ hp)
{
  int b  = blockIdx.x >> 6;          // batch
  int kq = blockIdx.x & 63;          // covers k = kq*4 .. kq*4+3
  __shared__ float xr[4][NDIN+1];
  for (int e = threadIdx.x; e < 4*NDIN; e += 64) {
    int row = e >> 9, col = e & 511;
    xr[row][col] = x[(size_t)(b*NK + kq*4 + row)*NDIN + col];
  }
  __syncthreads();
  int p = threadIdx.x;
  float bias = bp[p];
  float a0 = bias, a1 = bias, a2 = bias, a3 = bias;
  #pragma unroll 4
  for (int d = 0; d < NDIN; ++d) {
    float w = Wp[d*NPROJ + p];
    a0 += xr[0][d]*w; a1 += xr[1][d]*w; a2 += xr[2][d]*w; a3 += xr[3][d]*w;
  }
  float* dst = hp + (size_t)(b*NPROJ + p)*NK + kq*4;
  dst[0] = a0; dst[1] = a1; dst[2] = a2; dst[3] = a3;
}

// ---------------------------------------------------------------------------
// 2) u[n,t,m] (bf16) = sum_j hp[n][t*4+j] * We[j][m] + be[m]
//    64 rows per block; thread covers a 32-col strip of one row.
__global__ __launch_bounds__(256, 4) void k_embed(const float* __restrict__ hp,
                        const float* __restrict__ We,
                        const float* __restrict__ be, unsigned short* __restrict__ u)
{
  __shared__ float sWe[8][NDM];
  __shared__ float sbe[NDM];
  for (int e = threadIdx.x; e < 8*NDM; e += 256) sWe[e >> 7][e & 127] = We[e];
  if (threadIdx.x < NDM) sbe[threadIdx.x] = be[threadIdx.x];
  __syncthreads();
  int r = blockIdx.x*64 + (threadIdx.x >> 2);
  int strip = (threadIdx.x & 3) * 32;
  int n = r / NT, t = r - n*NT;
  const float* hr = hp + (size_t)n*NK + t*4;
  float h[8];
  #pragma unroll
  for (int j = 0; j < 8; ++j) h[j] = hr[j];
  float acc[32];
  #pragma unroll
  for (int c = 0; c < 32; ++c) acc[c] = sbe[strip + c];
  #pragma unroll
  for (int j = 0; j < 8; ++j)
    #pragma unroll
    for (int c = 0; c < 32; ++c)
      acc[c] += h[j] * sWe[j][strip + c];
  unsigned short* dst = u + (size_t)r*NDM + strip;
  #pragma unroll
  for (int g = 0; g < 4; ++g) {
    short8 o;
    #pragma unroll
    for (int i = 0; i < 8; ++i) o[i] = (short)f2bs(acc[g*8 + i]);
    *(short8*)&dst[g*8] = o;
  }
}

// ---------------------------------------------------------------------------
// 3) in_proj + fused rmsnorm. A (u bf16, 64 rows x K=128) staged ONCE into
//    LDS; loop the 4 B-tiles (512 N-cols) in-kernel.
__global__ __launch_bounds__(256) void k_inproj(
    const unsigned short* __restrict__ ub, const unsigned short* __restrict__ WT,
    unsigned short* __restrict__ xh, unsigned short* __restrict__ zb,
    const float* __restrict__ nw)
{
  __shared__ short As[64*LDP];
  __shared__ short Bs[128*LDP];
  const int tid  = threadIdx.x;
  const int r0   = blockIdx.x * 64;
  const int w    = tid >> 6;
  const int lane = tid & 63;
  const int l16  = lane & 15;
  const int quad = lane >> 4;
  const int WM   = (w >> 1) * 32;
  const int WN   = (w & 1) * 64;

  // ---- stage A once (64 rows x 128 k) with fused rmsnorm ----
  #pragma unroll
  for (int j = 0; j < 4; ++j) {
    int c = tid + j*256;
    int row = c >> 4, k8 = (c & 15) << 3;
    short8 vb = *(const short8*)&ub[(size_t)(r0+row)*128 + k8];
    float f[8];
    #pragma unroll
    for (int i = 0; i < 8; ++i) f[i] = bs2f((unsigned short)vb[i]);
    float ss = 0.f;
    #pragma unroll
    for (int i = 0; i < 8; ++i) ss += f[i]*f[i];
    #pragma unroll
    for (int m = 8; m >= 1; m >>= 1) ss += __shfl_xor(ss, m, 16);
    float sc = rsqrtf(ss*(1.f/128.f) + 1e-5f);
    const float4 nw0 = *(const float4*)&nw[k8];
    const float4 nw1 = *(const float4*)&nw[k8+4];
    short8 o;
    o[0] = (short)f2bs(f[0]*sc*nw0.x); o[1] = (short)f2bs(f[1]*sc*nw0.y);
    o[2] = (short)f2bs(f[2]*sc*nw0.z); o[3] = (short)f2bs(f[3]*sc*nw0.w);
    o[4] = (short)f2bs(f[4]*sc*nw1.x); o[5] = (short)f2bs(f[5]*sc*nw1.y);
    o[6] = (short)f2bs(f[6]*sc*nw1.z); o[7] = (short)f2bs(f[7]*sc*nw1.w);
    *(short8*)&As[row*LDP + k8] = o;
  }

  for (int ny = 0; ny < 4; ++ny) {
    if (ny) __syncthreads();
    #pragma unroll
    for (int j = 0; j < 8; ++j) {
      int c = tid + j*256;
      int n = c >> 4, k8 = (c & 15) << 3;
      *(short8*)&Bs[n*LDP + k8] =
          *(const short8*)&WT[(size_t)(ny*128 + n)*128 + k8];
    }
    __syncthreads();

    f32x4 acc[2][4] = {};
    #pragma unroll
    for (int ks = 0; ks < 4; ++ks) {
      short8 a[2], b[4];
      #pragma unroll
      for (int i = 0; i < 2; ++i)
        a[i] = *(const short8*)&As[(WM + i*16 + l16)*LDP + ks*32 + quad*8];
      #pragma unroll
      for (int j = 0; j < 4; ++j)
        b[j] = *(const short8*)&Bs[(WN + j*16 + l16)*LDP + ks*32 + quad*8];
      #pragma unroll
      for (int i = 0; i < 2; ++i)
        #pragma unroll
        for (int j = 0; j < 4; ++j)
          acc[i][j] = __builtin_amdgcn_mfma_f32_16x16x32_bf16(a[i], b[j], acc[i][j], 0, 0, 0);
    }
    #pragma unroll
    for (int i = 0; i < 2; ++i) {
      #pragma unroll
      for (int j = 0; j < 4; ++j) {
        #pragma unroll
        for (int rr = 0; rr < 4; ++rr) {
          int row = r0 + WM + i*16 + quad*4 + rr;
          int col = ny*128 + WN + j*16 + l16;
          float v = acc[i][j][rr];
          if (col < 256) xh[(size_t)row*256 + col]       = f2bs(v);
          else           zb[(size_t)row*256 + col - 256] = f2bs(v);
        }
      }
    }
  }
}

// ---------------------------------------------------------------------------
// 4) MFMA GEMM (x_proj / out_proj).
//    MODE 1: x_proj  : A = xh bf16 s256; B = WxT[64][256]; C f32 dbl(s40).
//    MODE 2: out_proj: A = xh bf16 s256; B = WoT[128][256]; u(bf16) += .
template<int MODE, int KTOT, int BN>
__global__ __launch_bounds__(256) void
k_mgemm(const void* __restrict__ Aptr, const unsigned short* __restrict__ WT,
        void* __restrict__ Cptr)
{
  constexpr int MJ = BN/32;
  __shared__ short As[64*LDP];
  __shared__ short Bs[BN*LDP];

  const int tid  = threadIdx.x;
  const int r0   = blockIdx.x * 64;
  const int w    = tid >> 6;
  const int lane = tid & 63;
  const int l16  = lane & 15;
  const int quad = lane >> 4;
  const int WM   = (w >> 1) * 32;
  const int WN   = (w & 1) * (BN/2);

  f32x4 acc[2][MJ] = {};

  for (int kc = 0; kc < KTOT; kc += 128) {
    #pragma unroll
    for (int j = 0; j < 4; ++j) {
      int c   = tid + j*256;
      int row = c >> 4, k8 = (c & 15) << 3;
      short8 v = *(const short8*)((const unsigned short*)Aptr
                                  + (size_t)(r0+row)*256 + kc + k8);
      *(short8*)&As[row*LDP + k8] = v;
    }
    #pragma unroll
    for (int j = 0; j < BN/16; ++j) {
      int c  = tid + j*256;
      int n  = c >> 4, k8 = (c & 15) << 3;
      short8 v = *(const short8*)(WT + (size_t)n*KTOT + kc + k8);
      *(short8*)&Bs[n*LDP + k8] = v;
    }
    __syncthreads();

    #pragma unroll
    for (int ks = 0; ks < 4; ++ks) {
      short8 a[2], b[MJ];
      #pragma unroll
      for (int i = 0; i < 2; ++i)
        a[i] = *(const short8*)&As[(WM + i*16 + l16)*LDP + ks*32 + quad*8];
      #pragma unroll
      for (int j = 0; j < MJ; ++j)
        b[j] = *(const short8*)&Bs[(WN + j*16 + l16)*LDP + ks*32 + quad*8];
      #pragma unroll
      for (int i = 0; i < 2; ++i)
        #pragma unroll
        for (int j = 0; j < MJ; ++j)
          acc[i][j] = __builtin_amdgcn_mfma_f32_16x16x32_bf16(a[i], b[j], acc[i][j], 0, 0, 0);
    }
    __syncthreads();
  }

  #pragma unroll
  for (int i = 0; i < 2; ++i) {
    #pragma unroll
    for (int j = 0; j < MJ; ++j) {
      #pragma unroll
      for (int rr = 0; rr < 4; ++rr) {
        int row = r0 + WM + i*16 + quad*4 + rr;
        int col = WN + j*16 + l16;
        float v = acc[i][j][rr];
        if (MODE == 1) {
          if (col < 40) ((float*)Cptr)[(size_t)row*40 + col] = v;
        } else {
          unsigned short* p = (unsigned short*)Cptr + (size_t)row*128 + col;
          *p = f2bs(bs2f(*p) + v);
        }
      }
    }
  }
}

// ---------------------------------------------------------------------------
// 5) depthwise causal conv(4) + bias + silu, IN PLACE on xh (stride 256).
__global__ __launch_bounds__(256, 8) void k_conv(bf16* __restrict__ xh,
                       const float* __restrict__ cw, const float* __restrict__ cb)
{
  int n = blockIdx.x, d = threadIdx.x;
  float w0 = cw[d*4+0], w1 = cw[d*4+1];
  float w2 = cw[d*4+2], w3 = cw[d*4+3];
  float bias = cb[d];
  float xm3 = 0.f, xm2 = 0.f, xm1 = 0.f;
  bf16* ptr = xh + (size_t)n*NT*256 + d;
  for (int t = 0; t < NT; ++t) {
    float xt = b2f(ptr[0]);
    float a  = bias + w0*xm3 + w1*xm2 + w2*xm1 + w3*xt;
    ptr[0] = f2b(siluf(a));
    ptr += 256;
    xm3 = xm2; xm2 = xm1; xm1 = xt;
  }
}

// ---------------------------------------------------------------------------
// 6) fused dt_proj + softplus + selective scan + skip + silu(z) gating.
//    launch_bounds(256,8): grid=8 blocks/CU needs exactly 8 waves/SIMD ->
//    VGPR cap 64 (prior build chose 32 and strangled the schedule).
//    Fast path: A[s]=-(s+1) => E=sigmoid(-dtv); powers via f32x4 chain;
//    all LDS reads as ds_read_b128 (rows of sd are 16B-aligned: 160B stride).
__global__ __launch_bounds__(256, 8) void k_scan(const float* __restrict__ dbl,
                       const bf16* __restrict__ z, bf16* __restrict__ xh,
                       const float* __restrict__ Wdt, const float* __restrict__ bdt,
                       const float* __restrict__ Alog, const float* __restrict__ Dpp)
{
  int n = blockIdx.x, d = threadIdx.x;
  __shared__ __align__(16) float sd[NT][40];    // dt(8) | B(16) | C(16)
  for (int i = threadIdx.x; i < NT*40; i += 256)
    sd[i/40][i%40] = dbl[(size_t)n*NT*40 + i];
  __syncthreads();

  float bd = bdt[d];
  float Av[16];
  #pragma unroll
  for (int s = 0; s < 16; ++s) Av[s] = -__expf(Alog[d*16 + s]);
  float Av0 = Av[0];
  bool chain = fabsf(Av0 + 1.f) <= 1e-3f;
  #pragma unroll
  for (int s = 0; s < 16; ++s)
    chain = chain && (fabsf(Av[s] - (float)(s+1)*Av0) <= 1e-3f*(float)(s+1));
  float dp = Dpp[d];

  const unsigned short* zp = (const unsigned short*)z + (size_t)n*NT*256 + d;
  unsigned short*       up = (unsigned short*)xh + (size_t)n*NT*256 + d;

  if (chain) {
    f32x2 wdt2[4];
    #pragma unroll
    for (int r = 0; r < 4; ++r) {
      f32x2 wv; wv.x = Wdt[(2*r)*256 + d]; wv.y = Wdt[(2*r+1)*256 + d];
      wdt2[r] = wv;
    }
    f32x4 h40 = {}, h41 = {}, h42 = {}, h43 = {};

    for (int t = 0; t < NT; ++t) {
      const f32x4* row = (const f32x4*)&sd[t][0];
      f32x4 dA = row[0], dB = row[1];
      f32x2 a2; a2.x = bd; a2.y = 0.f;
      f32x2 dl;
      dl.x = dA.x; dl.y = dA.y; a2 += dl*wdt2[0];
      dl.x = dA.z; dl.y = dA.w; a2 += dl*wdt2[1];
      dl.x = dB.x; dl.y = dB.y; a2 += dl*wdt2[2];
      dl.x = dB.z; dl.y = dB.w; a2 += dl*wdt2[3];
      float dtv = a2.x + a2.y;
      // E = sigmoid(-dtv), delta = softplus(dtv), branchless & overflow-safe
      float q  = __expf(-fabsf(dtv));
      float r1 = __builtin_amdgcn_rcpf(1.f + q);
      float E  = dtv > 0.f ? q*r1 : r1;
      float delta = fmaxf(dtv, 0.f) - __logf(r1);
      float E2 = E*E, E3 = E2*E, E4 = E2*E2;
      f32x4 p0; p0.x = E; p0.y = E2; p0.z = E3; p0.w = E4;
      f32x4 e4; e4.x = E4; e4.y = E4; e4.z = E4; e4.w = E4;
      f32x4 p1 = p0*e4, p2 = p1*e4, p3 = p2*e4;

      float ut = bs2f(*up);
      float du = delta*ut;
      f32x4 du4; du4.x = du; du4.y = du; du4.z = du; du4.w = du;
      h40 = h40*p0 + du4*row[2];
      h41 = h41*p1 + du4*row[3];
      h42 = h42*p2 + du4*row[4];
      h43 = h43*p3 + du4*row[5];
      f32x4 y4 = h40*row[6];
      y4 += h41*row[7];
      y4 += h42*row[8];
      y4 += h43*row[9];
      float yt = (y4.x + y4.y) + (y4.z + y4.w);
      float zv = bs2f(*zp);
      float y  = (yt + ut*dp) * siluf(zv);
      *up = f2bs(y);
      up += 256; zp += 256;
    }
  } else {
    float wdt[8];
    #pragma unroll
    for (int r = 0; r < 8; ++r) wdt[r] = Wdt[r*256 + d];
    float h[16];
    #pragma unroll
    for (int s = 0; s < 16; ++s) h[s] = 0.f;
    for (int t = 0; t < NT; ++t) {
      float dtv = bd;
      #pragma unroll
      for (int r = 0; r < 8; ++r) dtv += sd[t][r]*wdt[r];
      float delta = softplusf(dtv);
      float ut = bs2f(up[t*256]);
      float du = delta*ut;
      float yt = 0.f;
      #pragma unroll
      for (int s = 0; s < 16; ++s) {
        float e = __expf(delta*Av[s]);
        h[s] = h[s]*e + du*sd[t][8+s];
        yt  += h[s]*sd[t][24+s];
      }
      float zv = bs2f(zp[t*256]);
      float y  = (yt + ut*dp) * siluf(zv);
      up[t*256] = f2bs(y);
    }
  }
}

// ---------------------------------------------------------------------------
// 7) final rmsnorm + flat head. One wave per (n,t) row; u is bf16.
__global__ __launch_bounds__(256) void k_head(const unsigned short* __restrict__ u,
                       const float* __restrict__ fnw,
                       const float* __restrict__ hw, const float* __restrict__ hfb,
                       float* __restrict__ y1)
{
  int n = blockIdx.x;
  int w = threadIdx.x >> 6, lane = threadIdx.x & 63;
  const float2 fw = *(const float2*)&fnw[lane*2];
  float acc = 0.f;
  for (int t = w; t < NT; t += 4) {
    const ushort2 vb = *(const ushort2*)&u[((size_t)n*NT + t)*NDM + lane*2];
    float vx = bs2f(vb.x), vy = bs2f(vb.y);
    const float2 hv = *(const float2*)&hw[t*NDM + lane*2];
    float ss = vx*vx + vy*vy;
    #pragma unroll
    for (int o = 32; o >= 1; o >>= 1) ss += __shfl_xor(ss, o);
    float sc = rsqrtf(ss*(1.f/128.f) + 1e-5f);
    acc += (vx*fw.x*hv.x + vy*fw.y*hv.y)*sc;
  }
  #pragma unroll
  for (int o = 32; o >= 1; o >>= 1) acc += __shfl_xor(acc, o);
  __shared__ float ws[4];
  if (lane == 0) ws[w] = acc;
  __syncthreads();
  if (threadIdx.x == 0) y1[n] = ws[0] + ws[1] + ws[2] + ws[3] + hfb[0];
}

// ---------------------------------------------------------------------------
// 8) out[b,c] = sum_p y1[b*64+p]*Wh[p,c] + bh[c].
__global__ __launch_bounds__(64) void k_final(const float* __restrict__ y1,
                        const float* __restrict__ Wh,
                        const float* __restrict__ bh, float* __restrict__ out)
{
  int t = threadIdx.x;
  int b = t >> 1, c = t & 1;
  float acc = bh[c];
  #pragma unroll 8
  for (int p = 0; p < 64; ++p) acc += y1[b*64 + p]*Wh[p*2 + c];
  out[b*2 + c] = acc;
}

// ---------------------------------------------------------------------------
extern "C" void kernel_launch(void* const* d_in, const int* in_sizes, int n_in,
                              void* d_out, int out_size, void* d_ws, size_t ws_size,
                              hipStream_t stream)
{
  const float* x    = (const float*)d_in[0];
  const float* Wp   = (const float*)d_in[1];
  const float* bp   = (const float*)d_in[2];
  const float* We   = (const float*)d_in[3];
  const float* be   = (const float*)d_in[4];
  const float* nrm  = (const float*)d_in[5];
  const float* Wi   = (const float*)d_in[6];
  const float* cw   = (const float*)d_in[7];
  const float* cb   = (const float*)d_in[8];
  const float* Wx   = (const float*)d_in[9];
  const float* Wdt  = (const float*)d_in[10];
  const float* bdt  = (const float*)d_in[11];
  const float* Alog = (const float*)d_in[12];
  const float* Dpp  = (const float*)d_in[13];
  const float* Wo   = (const float*)d_in[14];
  const float* fnw  = (const float*)d_in[15];
  const float* hw   = (const float*)d_in[16];
  const float* hfb  = (const float*)d_in[17];
  const float* Wh   = (const float*)d_in[18];
  const float* bh   = (const float*)d_in[19];

  // ---- workspace layout + adaptive chunking (u bf16) ----
  const size_t wt_per_l = (size_t)512*128 + 128*256 + 64*256;   // shorts
  const size_t fixed_b = (size_t)NROW*NDM*2 + (size_t)NSEQ*NK*4 + NSEQ*4
                       + wt_per_l*2*NNL + 8192;
  const size_t per_seq = (size_t)NT*256*2*2 + (size_t)NT*40*4;
  int ch_seq = NSEQ;
  while (ch_seq > 128 && fixed_b + (size_t)ch_seq*per_seq + 2048 > ws_size)
    ch_seq >>= 1;
  const int nchunk  = NSEQ / ch_seq;
  const int ch_rows = ch_seq * NT;
  fprintf(stderr, "[mamba] ws_size=%zu ch_seq=%d nchunk=%d\n", ws_size, ch_seq, nchunk);

  char* pw = (char*)d_ws;
  unsigned short* u = (unsigned short*)pw; pw += (size_t)NROW*NDM*2;
  float* hp   = (float*)pw; pw += (size_t)NSEQ*NK*4;
  float* y1   = (float*)pw; pw += (size_t)NSEQ*4;
  unsigned short* WiT = (unsigned short*)pw; pw += (size_t)NNL*512*128*2;
  unsigned short* WoT = (unsigned short*)pw; pw += (size_t)NNL*128*256*2;
  unsigned short* WxT = (unsigned short*)pw; pw += (size_t)NNL*64*256*2;
  float* dbl  = (float*)pw; pw += (size_t)ch_rows*40*4;
  bf16*  xh   = (bf16*)pw;  pw += (size_t)ch_rows*256*2;
  bf16*  z    = (bf16*)pw;  pw += (size_t)ch_rows*256*2;

  k_tw_all<<<3*704, 256, 0, stream>>>(Wi, Wo, Wx, WiT, WoT, WxT);
  k_proj <<<NB*64,   64, 0, stream>>>(x, Wp, bp, hp);
  k_embed<<<NROW/64, 256, 0, stream>>>(hp, We, be, u);

  for (int l = 0; l < NNL; ++l) {
    const float* nw_l  = nrm  + (size_t)l*NDM;
    const float* cw_l  = cw   + (size_t)l*NDI*4;
    const float* cb_l  = cb   + (size_t)l*NDI;
    const float* Wdt_l = Wdt  + (size_t)l*8*NDI;
    const float* bdt_l = bdt  + (size_t)l*NDI;
    const float* Al_l  = Alog + (size_t)l*NDI*16;
    const float* Dp_l  = Dpp  + (size_t)l*NDI;
    const unsigned short* WiT_l = WiT + (size_t)l*512*128;
    const unsigned short* WoT_l = WoT + (size_t)l*128*256;
    const unsigned short* WxT_l = WxT + (size_t)l*64*256;

    for (int c = 0; c < nchunk; ++c) {
      unsigned short* u_c = u + (size_t)c*ch_rows*NDM;
      k_inproj<<<ch_rows/64, 256, 0, stream>>>(
          u_c, WiT_l, (unsigned short*)xh, (unsigned short*)z, nw_l);
      k_conv<<<ch_seq, 256, 0, stream>>>(xh, cw_l, cb_l);
      k_mgemm<1,256,64><<<ch_rows/64, 256, 0, stream>>>(xh, WxT_l, dbl);
      k_scan<<<ch_seq, 256, 0, stream>>>(dbl, z, xh, Wdt_l, bdt_l, Al_l, Dp_l);
      k_mgemm<2,256,128><<<ch_rows/64, 256, 0, stream>>>(xh, WoT_l, u_c);
    }
  }

  k_head <<<NSEQ, 256, 0, stream>>>(u, fnw, hw, hfb, y1);
  k_final<<<1, 64, 0, stream>>>(y1, Wh, bh, (float*)d_out);
}